// Round 2
// baseline (3645.822 us; speedup 1.0000x reference)
//
#include <hip/hip_runtime.h>
#include <hip/hip_bf16.h>
#include <math.h>

// Problem constants (B=1)
#define T_DIM 2048
#define D_DIM 2048
#define N_HEADS 16
#define K_HEADS 8
#define H_DIM 128
#define WINDOW_SZ 1024
#define SOFT_CAP 50.0f
#define Q_SCALE 0.08838834764831845f   // 1/sqrt(128)
#define LN_BASE 9.210340371976184f     // ln(10000)

// ---------------------------------------------------------------------------
// Kernel 1: fused QKV projection GEMM (fp32).
// C[t, c] for c in [0,4096): c<2048 -> q (n=c>>7, h=c&127)
//                            c<3072 -> k (kh=(c-2048)>>7)
//                            else   -> v (kh=(c-3072)>>7)
// A = x (T x D, fp32 row-major). Weights: q_kernel (N,D,H), kv_kernel (2,K,D,H).
// 64x64 tile, 256 threads, 4x4 per thread.
// ---------------------------------------------------------------------------
__global__ __launch_bounds__(256) void qkv_gemm_k(
    const float* __restrict__ x, const float* __restrict__ qk,
    const float* __restrict__ kvk,
    float* __restrict__ qbuf, float* __restrict__ kbuf, float* __restrict__ vbuf)
{
    __shared__ float As[16][65];
    __shared__ float Bs[16][65];
    const int tid = threadIdx.x;
    const int tx = tid & 15, ty = tid >> 4;
    const int row0 = blockIdx.x * 64;
    const int col0 = blockIdx.y * 64;   // 64-aligned; never straddles q/k/v boundaries

    float acc[4][4] = {};

    for (int k0 = 0; k0 < D_DIM; k0 += 16) {
#pragma unroll
        for (int i = 0; i < 4; ++i) {
            int idx = tid + i * 256;            // 0..1023
            int r = idx >> 4, c = idx & 15;     // 64 rows x 16 cols
            As[c][r] = x[(size_t)(row0 + r) * D_DIM + k0 + c];
        }
#pragma unroll
        for (int i = 0; i < 4; ++i) {
            int idx = tid + i * 256;
            int r = idx >> 6, c = idx & 63;     // 16 rows x 64 cols
            int gc = col0 + c;
            int d  = k0 + r;
            const float* wp;
            if (gc < 2048) {
                int n = gc >> 7, h = gc & 127;
                wp = qk + ((size_t)n * D_DIM + d) * H_DIM + h;
            } else if (gc < 3072) {
                int kh = (gc - 2048) >> 7, h = gc & 127;
                wp = kvk + ((size_t)kh * D_DIM + d) * H_DIM + h;
            } else {
                int kh = (gc - 3072) >> 7, h = gc & 127;
                wp = kvk + ((size_t)(K_HEADS + kh) * D_DIM + d) * H_DIM + h;
            }
            Bs[r][c] = *wp;
        }
        __syncthreads();
#pragma unroll
        for (int kk = 0; kk < 16; ++kk) {
            float a[4], b[4];
#pragma unroll
            for (int i = 0; i < 4; ++i) a[i] = As[kk][ty * 4 + i];
#pragma unroll
            for (int j = 0; j < 4; ++j) b[j] = Bs[kk][tx * 4 + j];
#pragma unroll
            for (int i = 0; i < 4; ++i)
#pragma unroll
                for (int j = 0; j < 4; ++j) acc[i][j] += a[i] * b[j];
        }
        __syncthreads();
    }

#pragma unroll
    for (int i = 0; i < 4; ++i) {
        int t = row0 + ty * 4 + i;
#pragma unroll
        for (int j = 0; j < 4; ++j) {
            int gc = col0 + tx * 4 + j;
            float v = acc[i][j];
            if (gc < 2048)      qbuf[(size_t)t * 2048 + gc]          = v;
            else if (gc < 3072) kbuf[(size_t)t * 1024 + (gc - 2048)] = v;
            else                vbuf[(size_t)t * 1024 + (gc - 3072)] = v;
        }
    }
}

// ---------------------------------------------------------------------------
// Kernel 2: RoPE in-place on q (with Q_SCALE) and k (fp32).
// One block per t. 1024 q-pairs + 512 k-pairs.
// ---------------------------------------------------------------------------
__global__ __launch_bounds__(256) void rope_k(
    float* __restrict__ qbuf, float* __restrict__ kbuf, const int* __restrict__ segpos)
{
    const int t = blockIdx.x;
    const float pos = (float)segpos[t];
    for (int p = threadIdx.x; p < 1536; p += 256) {
        float* buf; int hp; float scale;
        if (p < 1024) {
            int head = p >> 6; hp = p & 63;
            buf = qbuf + (size_t)t * 2048 + head * 128; scale = Q_SCALE;
        } else {
            int pp = p - 1024; int head = pp >> 6; hp = pp & 63;
            buf = kbuf + (size_t)t * 1024 + head * 128; scale = 1.0f;
        }
        float fraction = (float)hp * (1.0f / 64.0f);      // 2*hp/128
        float inv_ts = expf(-fraction * LN_BASE);         // 1 / 10000^fraction
        float ang = pos * inv_ts;
        float sv, cv; sincosf(ang, &sv, &cv);
        float first  = buf[hp];
        float second = buf[hp + 64];
        buf[hp]      = (first * cv - second * sv) * scale;
        buf[hp + 64] = (second * cv + first * sv) * scale;
    }
}

// ---------------------------------------------------------------------------
// Kernel 3: windowed attention, one block per (t, n) (fp32).
// Valid keys: s in [max(0, t-1023), t].
// ---------------------------------------------------------------------------
__global__ __launch_bounds__(256) void attn_k(
    const float* __restrict__ qbuf, const float* __restrict__ kbuf,
    const float* __restrict__ vbuf, float* __restrict__ ebuf)
{
    const int t = blockIdx.x;
    const int n = blockIdx.y;
    const int kh = n >> 1;               // G=2
    const int tid = threadIdx.x;
    const int lane = tid & 63;
    const int wave = tid >> 6;           // 0..3

    __shared__ float qs[128];
    __shared__ float logits[WINDOW_SZ];
    __shared__ float red[16];
    __shared__ float pv[256];

    if (tid < 128) qs[tid] = qbuf[(size_t)t * 2048 + n * 128 + tid];
    __syncthreads();

    int s_lo = t - (WINDOW_SZ - 1); if (s_lo < 0) s_lo = 0;
    const int M = t - s_lo + 1;

    // ---- logits: one wave per key position ----
    for (int i = wave; i < M; i += 4) {
        int s = s_lo + i;
        const float* kp = kbuf + (size_t)s * 1024 + kh * 128;
        float partial = qs[lane] * kp[lane] + qs[lane + 64] * kp[lane + 64];
#pragma unroll
        for (int off = 32; off > 0; off >>= 1) partial += __shfl_down(partial, off, 64);
        if (lane == 0)
            logits[i] = tanhf(partial * (1.0f / SOFT_CAP)) * SOFT_CAP;
    }
    __syncthreads();

    // ---- softmax (fp32) ----
    float lmax = -INFINITY;
    for (int i = tid; i < M; i += 256) lmax = fmaxf(lmax, logits[i]);
#pragma unroll
    for (int off = 32; off > 0; off >>= 1) lmax = fmaxf(lmax, __shfl_down(lmax, off, 64));
    if (lane == 0) red[wave] = lmax;
    __syncthreads();
    if (tid == 0) {
        float m = fmaxf(fmaxf(red[0], red[1]), fmaxf(red[2], red[3]));
        red[0] = m;
    }
    __syncthreads();
    lmax = red[0];

    float lsum = 0.0f;
    for (int i = tid; i < M; i += 256) {
        float e = expf(logits[i] - lmax);
        logits[i] = e;
        lsum += e;
    }
#pragma unroll
    for (int off = 32; off > 0; off >>= 1) lsum += __shfl_down(lsum, off, 64);
    if (lane == 0) red[8 + wave] = lsum;
    __syncthreads();
    if (tid == 0) red[8] = 1.0f / (red[8] + red[9] + red[10] + red[11]);
    __syncthreads();
    const float inv = red[8];

    // ---- PV: 2 threads per output h, each covers half the keys ----
    const int h = tid & 127, half = tid >> 7;
    float acc = 0.0f;
    for (int i = half; i < M; i += 2) {
        int s = s_lo + i;
        acc += logits[i] * vbuf[(size_t)s * 1024 + kh * 128 + h];
    }
    pv[tid] = acc;
    __syncthreads();
    if (tid < 128)
        ebuf[(size_t)t * 2048 + n * 128 + tid] = (pv[tid] + pv[tid + 128]) * inv;
}

// ---------------------------------------------------------------------------
// Kernel 4: output projection GEMM (fp32).
// out[t,d] = sum_c ebuf[t,c] * Wo[c,d], Wo row-major (c = n*128+h, d).
// ---------------------------------------------------------------------------
__global__ __launch_bounds__(256) void out_gemm_k(
    const float* __restrict__ A, const float* __restrict__ Bw, float* __restrict__ Cout)
{
    __shared__ float As[16][65];
    __shared__ float Bs[16][65];
    const int tid = threadIdx.x;
    const int tx = tid & 15, ty = tid >> 4;
    const int row0 = blockIdx.x * 64;
    const int col0 = blockIdx.y * 64;

    float acc[4][4] = {};

    for (int k0 = 0; k0 < 2048; k0 += 16) {
#pragma unroll
        for (int i = 0; i < 4; ++i) {
            int idx = tid + i * 256;
            int r = idx >> 4, c = idx & 15;
            As[c][r] = A[(size_t)(row0 + r) * 2048 + k0 + c];
        }
#pragma unroll
        for (int i = 0; i < 4; ++i) {
            int idx = tid + i * 256;
            int r = idx >> 6, c = idx & 63;
            Bs[r][c] = Bw[(size_t)(k0 + r) * 2048 + col0 + c];
        }
        __syncthreads();
#pragma unroll
        for (int kk = 0; kk < 16; ++kk) {
            float a[4], b[4];
#pragma unroll
            for (int i = 0; i < 4; ++i) a[i] = As[kk][ty * 4 + i];
#pragma unroll
            for (int j = 0; j < 4; ++j) b[j] = Bs[kk][tx * 4 + j];
#pragma unroll
            for (int i = 0; i < 4; ++i)
#pragma unroll
                for (int j = 0; j < 4; ++j) acc[i][j] += a[i] * b[j];
        }
        __syncthreads();
    }

#pragma unroll
    for (int i = 0; i < 4; ++i) {
        int t = row0 + ty * 4 + i;
#pragma unroll
        for (int j = 0; j < 4; ++j)
            Cout[(size_t)t * 2048 + col0 + tx * 4 + j] = acc[i][j];
    }
}

// ---------------------------------------------------------------------------
extern "C" void kernel_launch(void* const* d_in, const int* in_sizes, int n_in,
                              void* d_out, int out_size, void* d_ws, size_t ws_size,
                              hipStream_t stream)
{
    const float* x   = (const float*)d_in[0];
    const int*  segp = (const int*)d_in[1];
    // d_in[2] = attn_mask (bool) -- redundant with causal+window predicate, ignored
    const float* qk  = (const float*)d_in[3];
    const float* kvk = (const float*)d_in[4];
    const float* ok  = (const float*)d_in[5];

    // Workspace layout (fp32): q (T*N*H)=16MB, k (T*K*H)=8MB, v=8MB, e=16MB
    float* qbuf = (float*)d_ws;
    float* kbuf = qbuf + (size_t)T_DIM * N_HEADS * H_DIM;
    float* vbuf = kbuf + (size_t)T_DIM * K_HEADS * H_DIM;
    float* ebuf = vbuf + (size_t)T_DIM * K_HEADS * H_DIM;
    float* outp = (float*)d_out;

    qkv_gemm_k<<<dim3(T_DIM / 64, 4096 / 64), dim3(256), 0, stream>>>(
        x, qk, kvk, qbuf, kbuf, vbuf);
    rope_k<<<dim3(T_DIM), dim3(256), 0, stream>>>(qbuf, kbuf, segp);
    attn_k<<<dim3(T_DIM, N_HEADS), dim3(256), 0, stream>>>(qbuf, kbuf, vbuf, ebuf);
    out_gemm_k<<<dim3(T_DIM / 64, 2048 / 64), dim3(256), 0, stream>>>(ebuf, ok, outp);
}

// Round 3
// 1239.467 us; speedup vs baseline: 2.9414x; 2.9414x over previous
//
#include <hip/hip_runtime.h>
#include <hip/hip_bf16.h>
#include <math.h>

// Problem constants (B=1)
#define T_DIM 2048
#define D_DIM 2048
#define N_HEADS 16
#define K_HEADS 8
#define H_DIM 128
#define WINDOW_SZ 1024
#define SOFT_CAP 50.0f
#define Q_SCALE 0.08838834764831845f   // 1/sqrt(128)
#define LN_BASE 9.210340371976184f     // ln(10000)

typedef __attribute__((ext_vector_type(8))) short short8;
typedef __attribute__((ext_vector_type(4))) float floatx4;

static __device__ __forceinline__ unsigned short f2u(float f) {
    __hip_bfloat16 h = __float2bfloat16(f);
    return *reinterpret_cast<unsigned short*>(&h);
}
static __device__ __forceinline__ short f2bs(float f) { return (short)f2u(f); }
static __device__ __forceinline__ unsigned pack2(float a, float b) {
    return (unsigned)f2u(a) | ((unsigned)f2u(b) << 16);
}

// ---------------------------------------------------------------------------
// Kernel 1: fused QKV projection GEMM (fp32). (unchanged from round 2)
// ---------------------------------------------------------------------------
__global__ __launch_bounds__(256) void qkv_gemm_k(
    const float* __restrict__ x, const float* __restrict__ qk,
    const float* __restrict__ kvk,
    float* __restrict__ qbuf, float* __restrict__ kbuf, float* __restrict__ vbuf)
{
    __shared__ float As[16][65];
    __shared__ float Bs[16][65];
    const int tid = threadIdx.x;
    const int tx = tid & 15, ty = tid >> 4;
    const int row0 = blockIdx.x * 64;
    const int col0 = blockIdx.y * 64;

    float acc[4][4] = {};

    for (int k0 = 0; k0 < D_DIM; k0 += 16) {
#pragma unroll
        for (int i = 0; i < 4; ++i) {
            int idx = tid + i * 256;
            int r = idx >> 4, c = idx & 15;
            As[c][r] = x[(size_t)(row0 + r) * D_DIM + k0 + c];
        }
#pragma unroll
        for (int i = 0; i < 4; ++i) {
            int idx = tid + i * 256;
            int r = idx >> 6, c = idx & 63;
            int gc = col0 + c;
            int d  = k0 + r;
            const float* wp;
            if (gc < 2048) {
                int nn = gc >> 7, h = gc & 127;
                wp = qk + ((size_t)nn * D_DIM + d) * H_DIM + h;
            } else if (gc < 3072) {
                int kh = (gc - 2048) >> 7, h = gc & 127;
                wp = kvk + ((size_t)kh * D_DIM + d) * H_DIM + h;
            } else {
                int kh = (gc - 3072) >> 7, h = gc & 127;
                wp = kvk + ((size_t)(K_HEADS + kh) * D_DIM + d) * H_DIM + h;
            }
            Bs[r][c] = *wp;
        }
        __syncthreads();
#pragma unroll
        for (int kk = 0; kk < 16; ++kk) {
            float a[4], b[4];
#pragma unroll
            for (int i = 0; i < 4; ++i) a[i] = As[kk][ty * 4 + i];
#pragma unroll
            for (int j = 0; j < 4; ++j) b[j] = Bs[kk][tx * 4 + j];
#pragma unroll
            for (int i = 0; i < 4; ++i)
#pragma unroll
                for (int j = 0; j < 4; ++j) acc[i][j] += a[i] * b[j];
        }
        __syncthreads();
    }

#pragma unroll
    for (int i = 0; i < 4; ++i) {
        int t = row0 + ty * 4 + i;
#pragma unroll
        for (int j = 0; j < 4; ++j) {
            int gc = col0 + tx * 4 + j;
            float v = acc[i][j];
            if (gc < 2048)      qbuf[(size_t)t * 2048 + gc]          = v;
            else if (gc < 3072) kbuf[(size_t)t * 1024 + (gc - 2048)] = v;
            else                vbuf[(size_t)t * 1024 + (gc - 3072)] = v;
        }
    }
}

// ---------------------------------------------------------------------------
// Kernel 2: RoPE in-place on q (with Q_SCALE) and k (fp32). (unchanged)
// ---------------------------------------------------------------------------
__global__ __launch_bounds__(256) void rope_k(
    float* __restrict__ qbuf, float* __restrict__ kbuf, const int* __restrict__ segpos)
{
    const int t = blockIdx.x;
    const float pos = (float)segpos[t];
    for (int p = threadIdx.x; p < 1536; p += 256) {
        float* buf; int hp; float scale;
        if (p < 1024) {
            int head = p >> 6; hp = p & 63;
            buf = qbuf + (size_t)t * 2048 + head * 128; scale = Q_SCALE;
        } else {
            int pp = p - 1024; int head = pp >> 6; hp = pp & 63;
            buf = kbuf + (size_t)t * 1024 + head * 128; scale = 1.0f;
        }
        float fraction = (float)hp * (1.0f / 64.0f);
        float inv_ts = expf(-fraction * LN_BASE);
        float ang = pos * inv_ts;
        float sv, cv; sincosf(ang, &sv, &cv);
        float first  = buf[hp];
        float second = buf[hp + 64];
        buf[hp]      = (first * cv - second * sv) * scale;
        buf[hp + 64] = (second * cv + first * sv) * scale;
    }
}

// ---------------------------------------------------------------------------
// Kernel 3: flash-style MFMA attention.
// Block: 64 q-rows (t0..t0+63) x 1 head. 4 waves x 16 rows.
// Iterate 32-key chunks over [max(0,t0-1023) & ~31, t0+63].
// MFMA 16x16x32 bf16. Layouts (guide-verified):
//   A[m=lane&15][k=(lane>>4)*8+j], B[k=(lane>>4)*8+j][n=lane&15],
//   C/D: col=lane&15, row=(lane>>4)*4+reg.
// ---------------------------------------------------------------------------
__global__ __launch_bounds__(256) void attn_k(
    const float* __restrict__ qbuf, const float* __restrict__ kbuf,
    const float* __restrict__ vbuf, float* __restrict__ ebuf)
{
    __shared__ alignas(16) __hip_bfloat16 Ks[32][136];  // [key][hd], pad 8 -> 2-way on b128 reads
    __shared__ alignas(16) __hip_bfloat16 Vt[128][40];  // [hd][key], pad 8 -> 2-way on b128 reads
    __shared__ alignas(16) __hip_bfloat16 Ps[4][16][48];// per-wave P, [row][key], pad for writes

    const int t0 = blockIdx.x * 64;
    const int n  = blockIdx.y;
    const int kh = n >> 1;               // G=2
    const int tid  = threadIdx.x;
    const int lane = tid & 63;
    const int wave = tid >> 6;
    const int lo   = lane & 15;
    const int quad = lane >> 4;

    // ---- Q fragments (A-layout): rows t0+wave*16+lo, head n, 4 k-chunks of 32 ----
    short8 qf[4];
    {
        const float* qp = qbuf + (size_t)(t0 + wave * 16 + lo) * 2048 + n * 128;
#pragma unroll
        for (int kc = 0; kc < 4; ++kc) {
            float4 x0 = *(const float4*)(qp + kc * 32 + quad * 8);
            float4 x1 = *(const float4*)(qp + kc * 32 + quad * 8 + 4);
            short8 f;
            f[0] = f2bs(x0.x); f[1] = f2bs(x0.y); f[2] = f2bs(x0.z); f[3] = f2bs(x0.w);
            f[4] = f2bs(x1.x); f[5] = f2bs(x1.y); f[6] = f2bs(x1.z); f[7] = f2bs(x1.w);
            qf[kc] = f;
        }
    }

    floatx4 O[8];
#pragma unroll
    for (int i = 0; i < 8; ++i) O[i] = (floatx4){0.f, 0.f, 0.f, 0.f};
    float m_run[4] = {-1e30f, -1e30f, -1e30f, -1e30f};
    float l_run[4] = {0.f, 0.f, 0.f, 0.f};

    const int key = tid >> 3;            // 0..31 (staging)
    const int hd0 = (tid & 7) * 16;      // 0..112 (staging)
    const int t_hi = t0 + 63;
    const int s_start = (t0 > 1023) ? ((t0 - 1023) & ~31) : 0;
    const int twlo = t0 + wave * 16;

    for (int base = s_start; base <= t_hi; base += 32) {
        __syncthreads();   // protect LDS from previous iteration's readers
        // ---- stage K chunk (bf16, [key][hd]) and V chunk transposed ([hd][key]) ----
        {
            const float* kp = kbuf + (size_t)(base + key) * 1024 + kh * 128 + hd0;
            float4 a = ((const float4*)kp)[0];
            float4 b = ((const float4*)kp)[1];
            float4 c = ((const float4*)kp)[2];
            float4 d = ((const float4*)kp)[3];
            unsigned* dst = (unsigned*)&Ks[key][hd0];
            dst[0] = pack2(a.x, a.y); dst[1] = pack2(a.z, a.w);
            dst[2] = pack2(b.x, b.y); dst[3] = pack2(b.z, b.w);
            dst[4] = pack2(c.x, c.y); dst[5] = pack2(c.z, c.w);
            dst[6] = pack2(d.x, d.y); dst[7] = pack2(d.z, d.w);

            const float* vp = vbuf + (size_t)(base + key) * 1024 + kh * 128 + hd0;
            float4 e = ((const float4*)vp)[0];
            float4 f = ((const float4*)vp)[1];
            float4 g = ((const float4*)vp)[2];
            float4 h = ((const float4*)vp)[3];
            float vv[16] = {e.x, e.y, e.z, e.w, f.x, f.y, f.z, f.w,
                            g.x, g.y, g.z, g.w, h.x, h.y, h.z, h.w};
#pragma unroll
            for (int i = 0; i < 16; ++i) Vt[hd0 + i][key] = __float2bfloat16(vv[i]);
        }
        __syncthreads();

        // ---- per-wave compute; skip chunks irrelevant to this wave's 16 rows ----
        if (base <= twlo + 15 && base + 31 >= twlo - (WINDOW_SZ - 1)) {
            floatx4 S0 = (floatx4){0.f, 0.f, 0.f, 0.f};
            floatx4 S1 = (floatx4){0.f, 0.f, 0.f, 0.f};
#pragma unroll
            for (int kc = 0; kc < 4; ++kc) {
                short8 b0 = *(const short8*)&Ks[lo][kc * 32 + quad * 8];
                short8 b1 = *(const short8*)&Ks[16 + lo][kc * 32 + quad * 8];
                S0 = __builtin_amdgcn_mfma_f32_16x16x32_bf16(qf[kc], b0, S0, 0, 0, 0);
                S1 = __builtin_amdgcn_mfma_f32_16x16x32_bf16(qf[kc], b1, S1, 0, 0, 0);
            }

            // ---- softcap + mask (registers, C-layout) ----
            float lg[2][4];
#pragma unroll
            for (int tau = 0; tau < 2; ++tau) {
#pragma unroll
                for (int r = 0; r < 4; ++r) {
                    float sv = (tau == 0) ? S0[r] : S1[r];
                    float ax = fabsf(sv) * (2.0f / SOFT_CAP);
                    float e2 = __expf(-ax);
                    float th = (1.0f - e2) / (1.0f + e2);
                    float l  = copysignf(SOFT_CAP * th, sv);
                    int s_idx = base + tau * 16 + lo;
                    int t_idx = twlo + quad * 4 + r;
                    bool valid = (s_idx <= t_idx) && (s_idx > t_idx - WINDOW_SZ);
                    lg[tau][r] = valid ? l : -1e30f;
                }
            }

            // ---- online softmax: row = quad*4+r lives in the 16 lanes of this quad ----
            float rmax[4];
#pragma unroll
            for (int r = 0; r < 4; ++r) rmax[r] = fmaxf(lg[0][r], lg[1][r]);
#pragma unroll
            for (int xm = 1; xm < 16; xm <<= 1)
#pragma unroll
                for (int r = 0; r < 4; ++r)
                    rmax[r] = fmaxf(rmax[r], __shfl_xor(rmax[r], xm, 64));

            float alpha[4];
#pragma unroll
            for (int r = 0; r < 4; ++r) {
                float mn = fmaxf(m_run[r], rmax[r]);
                alpha[r] = __expf(m_run[r] - mn);
                m_run[r] = mn;
            }
#pragma unroll
            for (int tau = 0; tau < 2; ++tau)
#pragma unroll
                for (int r = 0; r < 4; ++r) {
                    float l = lg[tau][r];
                    lg[tau][r] = (l <= -1e29f) ? 0.f : __expf(l - m_run[r]);
                }
            float rsum[4];
#pragma unroll
            for (int r = 0; r < 4; ++r) rsum[r] = lg[0][r] + lg[1][r];
#pragma unroll
            for (int xm = 1; xm < 16; xm <<= 1)
#pragma unroll
                for (int r = 0; r < 4; ++r) rsum[r] += __shfl_xor(rsum[r], xm, 64);
#pragma unroll
            for (int r = 0; r < 4; ++r) l_run[r] = l_run[r] * alpha[r] + rsum[r];

            // rescale O
#pragma unroll
            for (int th8 = 0; th8 < 8; ++th8)
#pragma unroll
                for (int r = 0; r < 4; ++r) O[th8][r] *= alpha[r];

            // ---- P -> LDS (C-layout scatter), read back in A-layout (wave-local) ----
#pragma unroll
            for (int tau = 0; tau < 2; ++tau)
#pragma unroll
                for (int r = 0; r < 4; ++r)
                    Ps[wave][quad * 4 + r][tau * 16 + lo] = __float2bfloat16(lg[tau][r]);

            short8 pfrag = *(const short8*)&Ps[wave][lo][quad * 8];
#pragma unroll
            for (int th8 = 0; th8 < 8; ++th8) {
                short8 vfrag = *(const short8*)&Vt[th8 * 16 + lo][quad * 8];
                O[th8] = __builtin_amdgcn_mfma_f32_16x16x32_bf16(pfrag, vfrag, O[th8], 0, 0, 0);
            }
        }
    }

    // ---- epilogue: normalize and store (fp32) ----
#pragma unroll
    for (int th8 = 0; th8 < 8; ++th8) {
#pragma unroll
        for (int r = 0; r < 4; ++r) {
            int t = twlo + quad * 4 + r;
            ebuf[(size_t)t * 2048 + n * 128 + th8 * 16 + lo] = O[th8][r] / l_run[r];
        }
    }
}

// ---------------------------------------------------------------------------
// Kernel 4: output projection GEMM (fp32). (unchanged)
// ---------------------------------------------------------------------------
__global__ __launch_bounds__(256) void out_gemm_k(
    const float* __restrict__ A, const float* __restrict__ Bw, float* __restrict__ Cout)
{
    __shared__ float As[16][65];
    __shared__ float Bs[16][65];
    const int tid = threadIdx.x;
    const int tx = tid & 15, ty = tid >> 4;
    const int row0 = blockIdx.x * 64;
    const int col0 = blockIdx.y * 64;

    float acc[4][4] = {};

    for (int k0 = 0; k0 < 2048; k0 += 16) {
#pragma unroll
        for (int i = 0; i < 4; ++i) {
            int idx = tid + i * 256;
            int r = idx >> 4, c = idx & 15;
            As[c][r] = A[(size_t)(row0 + r) * 2048 + k0 + c];
        }
#pragma unroll
        for (int i = 0; i < 4; ++i) {
            int idx = tid + i * 256;
            int r = idx >> 6, c = idx & 63;
            Bs[r][c] = Bw[(size_t)(k0 + r) * 2048 + col0 + c];
        }
        __syncthreads();
#pragma unroll
        for (int kk = 0; kk < 16; ++kk) {
            float a[4], b[4];
#pragma unroll
            for (int i = 0; i < 4; ++i) a[i] = As[kk][ty * 4 + i];
#pragma unroll
            for (int j = 0; j < 4; ++j) b[j] = Bs[kk][tx * 4 + j];
#pragma unroll
            for (int i = 0; i < 4; ++i)
#pragma unroll
                for (int j = 0; j < 4; ++j) acc[i][j] += a[i] * b[j];
        }
        __syncthreads();
    }

#pragma unroll
    for (int i = 0; i < 4; ++i) {
        int t = row0 + ty * 4 + i;
#pragma unroll
        for (int j = 0; j < 4; ++j)
            Cout[(size_t)t * 2048 + col0 + tx * 4 + j] = acc[i][j];
    }
}

// ---------------------------------------------------------------------------
extern "C" void kernel_launch(void* const* d_in, const int* in_sizes, int n_in,
                              void* d_out, int out_size, void* d_ws, size_t ws_size,
                              hipStream_t stream)
{
    const float* x   = (const float*)d_in[0];
    const int*  segp = (const int*)d_in[1];
    // d_in[2] = attn_mask (bool) -- redundant with causal+window predicate, ignored
    const float* qk  = (const float*)d_in[3];
    const float* kvk = (const float*)d_in[4];
    const float* ok  = (const float*)d_in[5];

    float* qbuf = (float*)d_ws;
    float* kbuf = qbuf + (size_t)T_DIM * N_HEADS * H_DIM;
    float* vbuf = kbuf + (size_t)T_DIM * K_HEADS * H_DIM;
    float* ebuf = vbuf + (size_t)T_DIM * K_HEADS * H_DIM;
    float* outp = (float*)d_out;

    qkv_gemm_k<<<dim3(T_DIM / 64, 4096 / 64), dim3(256), 0, stream>>>(
        x, qk, kvk, qbuf, kbuf, vbuf);
    rope_k<<<dim3(T_DIM), dim3(256), 0, stream>>>(qbuf, kbuf, segp);
    attn_k<<<dim3(T_DIM / 64, N_HEADS), dim3(256), 0, stream>>>(qbuf, kbuf, vbuf, ebuf);
    out_gemm_k<<<dim3(T_DIM / 64, 2048 / 64), dim3(256), 0, stream>>>(ebuf, ok, outp);
}

// Round 4
// 341.428 us; speedup vs baseline: 10.6782x; 3.6302x over previous
//
#include <hip/hip_runtime.h>
#include <hip/hip_bf16.h>
#include <math.h>

// Problem constants (B=1)
#define T_DIM 2048
#define D_DIM 2048
#define N_HEADS 16
#define K_HEADS 8
#define H_DIM 128
#define WINDOW_SZ 1024
#define SOFT_CAP 50.0f
#define Q_SCALE 0.08838834764831845f   // 1/sqrt(128)
#define LN_BASE 9.210340371976184f     // ln(10000)

typedef __hip_bfloat16 bf16;
typedef __attribute__((ext_vector_type(8))) short short8;
typedef __attribute__((ext_vector_type(4))) float floatx4;

static __device__ __forceinline__ bf16 f2b(float v) { return __float2bfloat16(v); }
static __device__ __forceinline__ float b2f(bf16 v) { return __bfloat162float(v); }

// ---------------------------------------------------------------------------
// Prep 1: x fp32 -> bf16 (elementwise, 8 per thread)
// ---------------------------------------------------------------------------
__global__ __launch_bounds__(256) void cvt_x_k(const float* __restrict__ x,
                                               bf16* __restrict__ xb)
{
    const size_t i = ((size_t)blockIdx.x * 256 + threadIdx.x) * 8;
    float4 a = *(const float4*)(x + i);
    float4 b = *(const float4*)(x + i + 4);
    bf16 o[8] = {f2b(a.x), f2b(a.y), f2b(a.z), f2b(a.w),
                 f2b(b.x), f2b(b.y), f2b(b.z), f2b(b.w)};
    *(short8*)(xb + i) = *(const short8*)o;
}

// ---------------------------------------------------------------------------
// Prep 2: tiled transpose + convert. dst[c][r] = src[r][c] per matrix.
// block (32x8)=256, grid (C/32, R/32, nmat).
// ---------------------------------------------------------------------------
__global__ __launch_bounds__(256) void transpose_cvt_k(
    const float* __restrict__ src, bf16* __restrict__ dst,
    int src_rstride, int dst_rstride, size_t src_mstride, size_t dst_mstride)
{
    __shared__ float tile[32][33];
    const int tx = threadIdx.x & 31, ty = threadIdx.x >> 5;
    const float* s = src + (size_t)blockIdx.z * src_mstride;
    bf16* d = dst + (size_t)blockIdx.z * dst_mstride;
    const int r0 = blockIdx.y * 32, c0 = blockIdx.x * 32;
#pragma unroll
    for (int i = 0; i < 4; ++i)
        tile[ty + i * 8][tx] = s[(size_t)(r0 + ty + i * 8) * src_rstride + c0 + tx];
    __syncthreads();
#pragma unroll
    for (int i = 0; i < 4; ++i)
        d[(size_t)(c0 + ty + i * 8) * dst_rstride + r0 + tx] = f2b(tile[tx][ty + i * 8]);
}

// ---------------------------------------------------------------------------
// MFMA GEMM (m97 structure): C[M,N] = A[M,K] * BT[N,K]^T, all bf16 in,
// CT out (bf16 or fp32). 128x128 tile, BK=32, 256 threads, 4 waves 2x2,
// each wave 4x4 of mfma_f32_16x16x32_bf16. global_load_lds width-16 staging.
// ---------------------------------------------------------------------------
template <typename CT>
__global__ __launch_bounds__(256) void mfma_gemm_k(
    const bf16* __restrict__ A, const bf16* __restrict__ BT,
    CT* __restrict__ C, int Ndim, int Kdim)
{
    __shared__ alignas(16) bf16 As[128 * 32];   // row-major [128][32], no pad (lds-dma layout)
    __shared__ alignas(16) bf16 Bs[128 * 32];

    const int tid  = threadIdx.x;
    const int lane = tid & 63;
    const int wave = tid >> 6;
    const int lo   = lane & 15;
    const int quad = lane >> 4;
    const int row0 = blockIdx.x * 128;
    const int col0 = blockIdx.y * 128;
    const int wm = (wave >> 1) * 64;
    const int wn = (wave & 1) * 64;

    // staging pattern: segment s = wave*2+i covers tile rows s*16 + lane/4,
    // col chunk (lane&3)*8; LDS byte offset s*1024 + lane*16.
    const int lrow = lane >> 2;
    const int lcol = (lane & 3) * 8;

    floatx4 acc[4][4];
#pragma unroll
    for (int i = 0; i < 4; ++i)
#pragma unroll
        for (int j = 0; j < 4; ++j) acc[i][j] = (floatx4){0.f, 0.f, 0.f, 0.f};

    for (int k0 = 0; k0 < Kdim; k0 += 32) {
        __syncthreads();
#pragma unroll
        for (int i = 0; i < 2; ++i) {
            const int trow = wave * 32 + i * 16 + lrow;
            const bf16* ga = A  + (size_t)(row0 + trow) * Kdim + k0 + lcol;
            const bf16* gb = BT + (size_t)(col0 + trow) * Kdim + k0 + lcol;
            __builtin_amdgcn_global_load_lds(
                (const __attribute__((address_space(1))) void*)ga,
                (__attribute__((address_space(3))) void*)(As + (wave * 2 + i) * 512),
                16, 0, 0);
            __builtin_amdgcn_global_load_lds(
                (const __attribute__((address_space(1))) void*)gb,
                (__attribute__((address_space(3))) void*)(Bs + (wave * 2 + i) * 512),
                16, 0, 0);
        }
        __syncthreads();

        short8 af[4], bfr[4];
#pragma unroll
        for (int mt = 0; mt < 4; ++mt)
            af[mt] = *(const short8*)&As[(wm + mt * 16 + lo) * 32 + quad * 8];
#pragma unroll
        for (int nt = 0; nt < 4; ++nt)
            bfr[nt] = *(const short8*)&Bs[(wn + nt * 16 + lo) * 32 + quad * 8];
#pragma unroll
        for (int mt = 0; mt < 4; ++mt)
#pragma unroll
            for (int nt = 0; nt < 4; ++nt)
                acc[mt][nt] = __builtin_amdgcn_mfma_f32_16x16x32_bf16(
                    af[mt], bfr[nt], acc[mt][nt], 0, 0, 0);
    }

#pragma unroll
    for (int mt = 0; mt < 4; ++mt)
#pragma unroll
        for (int nt = 0; nt < 4; ++nt)
#pragma unroll
            for (int r = 0; r < 4; ++r) {
                int rr = row0 + wm + mt * 16 + quad * 4 + r;
                int cc = col0 + wn + nt * 16 + lo;
                float v = acc[mt][nt][r];
                if constexpr (__is_same(CT, bf16)) C[(size_t)rr * Ndim + cc] = f2b(v);
                else                               C[(size_t)rr * Ndim + cc] = v;
            }
}

// ---------------------------------------------------------------------------
// RoPE in-place on qkvb (bf16, row stride 4096): q cols 0..2047 (scale),
// k cols 2048..3071. One block per t.
// ---------------------------------------------------------------------------
__global__ __launch_bounds__(256) void rope_k(bf16* __restrict__ qkvb,
                                              const int* __restrict__ segpos)
{
    const int t = blockIdx.x;
    const float pos = (float)segpos[t];
    bf16* rowp = qkvb + (size_t)t * 4096;
    for (int p = threadIdx.x; p < 1536; p += 256) {
        bf16* buf; int hp; float scale;
        if (p < 1024) {
            hp = p & 63;
            buf = rowp + (p >> 6) * 128; scale = Q_SCALE;
        } else {
            int pp = p - 1024; hp = pp & 63;
            buf = rowp + 2048 + (pp >> 6) * 128; scale = 1.0f;
        }
        float fraction = (float)hp * (1.0f / 64.0f);
        float inv_ts = expf(-fraction * LN_BASE);
        float ang = pos * inv_ts;
        float sv, cv; sincosf(ang, &sv, &cv);
        float first  = b2f(buf[hp]);
        float second = b2f(buf[hp + 64]);
        buf[hp]      = f2b((first * cv - second * sv) * scale);
        buf[hp + 64] = f2b((second * cv + first * sv) * scale);
    }
}

// ---------------------------------------------------------------------------
// Flash-style MFMA attention (round-3 verified), now on bf16 qkvb.
// Block: 64 q-rows x 1 head, 4 waves x 16 rows, 32-key chunks.
// ---------------------------------------------------------------------------
__global__ __launch_bounds__(256) void attn_k(
    const bf16* __restrict__ qkvb, bf16* __restrict__ ebuf)
{
    __shared__ alignas(16) bf16 Ks[32][136];
    __shared__ alignas(16) bf16 Vt[128][40];
    __shared__ alignas(16) bf16 Ps[4][16][48];

    const int t0 = blockIdx.x * 64;
    const int n  = blockIdx.y;
    const int kh = n >> 1;
    const int tid  = threadIdx.x;
    const int lane = tid & 63;
    const int wave = tid >> 6;
    const int lo   = lane & 15;
    const int quad = lane >> 4;

    short8 qf[4];
    {
        const bf16* qp = qkvb + (size_t)(t0 + wave * 16 + lo) * 4096 + n * 128;
#pragma unroll
        for (int kc = 0; kc < 4; ++kc)
            qf[kc] = *(const short8*)(qp + kc * 32 + quad * 8);
    }

    floatx4 O[8];
#pragma unroll
    for (int i = 0; i < 8; ++i) O[i] = (floatx4){0.f, 0.f, 0.f, 0.f};
    float m_run[4] = {-1e30f, -1e30f, -1e30f, -1e30f};
    float l_run[4] = {0.f, 0.f, 0.f, 0.f};

    const int key = tid >> 3;
    const int hd0 = (tid & 7) * 16;
    const int t_hi = t0 + 63;
    const int s_start = (t0 > 1023) ? ((t0 - 1023) & ~31) : 0;
    const int twlo = t0 + wave * 16;

    for (int base = s_start; base <= t_hi; base += 32) {
        __syncthreads();
        {
            const bf16* kp = qkvb + (size_t)(base + key) * 4096 + 2048 + kh * 128 + hd0;
            *(short8*)&Ks[key][hd0]     = *(const short8*)kp;
            *(short8*)&Ks[key][hd0 + 8] = *(const short8*)(kp + 8);

            const bf16* vp = qkvb + (size_t)(base + key) * 4096 + 3072 + kh * 128 + hd0;
            short8 v0 = *(const short8*)vp;
            short8 v1 = *(const short8*)(vp + 8);
            const bf16* vb0 = (const bf16*)&v0;
            const bf16* vb1 = (const bf16*)&v1;
#pragma unroll
            for (int i = 0; i < 8; ++i) Vt[hd0 + i][key]     = vb0[i];
#pragma unroll
            for (int i = 0; i < 8; ++i) Vt[hd0 + 8 + i][key] = vb1[i];
        }
        __syncthreads();

        if (base <= twlo + 15 && base + 31 >= twlo - (WINDOW_SZ - 1)) {
            floatx4 S0 = (floatx4){0.f, 0.f, 0.f, 0.f};
            floatx4 S1 = (floatx4){0.f, 0.f, 0.f, 0.f};
#pragma unroll
            for (int kc = 0; kc < 4; ++kc) {
                short8 b0 = *(const short8*)&Ks[lo][kc * 32 + quad * 8];
                short8 b1 = *(const short8*)&Ks[16 + lo][kc * 32 + quad * 8];
                S0 = __builtin_amdgcn_mfma_f32_16x16x32_bf16(qf[kc], b0, S0, 0, 0, 0);
                S1 = __builtin_amdgcn_mfma_f32_16x16x32_bf16(qf[kc], b1, S1, 0, 0, 0);
            }

            float lg[2][4];
#pragma unroll
            for (int tau = 0; tau < 2; ++tau) {
#pragma unroll
                for (int r = 0; r < 4; ++r) {
                    float sv = (tau == 0) ? S0[r] : S1[r];
                    float ax = fabsf(sv) * (2.0f / SOFT_CAP);
                    float e2 = __expf(-ax);
                    float th = (1.0f - e2) / (1.0f + e2);
                    float l  = copysignf(SOFT_CAP * th, sv);
                    int s_idx = base + tau * 16 + lo;
                    int t_idx = twlo + quad * 4 + r;
                    bool valid = (s_idx <= t_idx) && (s_idx > t_idx - WINDOW_SZ);
                    lg[tau][r] = valid ? l : -1e30f;
                }
            }

            float rmax[4];
#pragma unroll
            for (int r = 0; r < 4; ++r) rmax[r] = fmaxf(lg[0][r], lg[1][r]);
#pragma unroll
            for (int xm = 1; xm < 16; xm <<= 1)
#pragma unroll
                for (int r = 0; r < 4; ++r)
                    rmax[r] = fmaxf(rmax[r], __shfl_xor(rmax[r], xm, 64));

            float alpha[4];
#pragma unroll
            for (int r = 0; r < 4; ++r) {
                float mn = fmaxf(m_run[r], rmax[r]);
                alpha[r] = __expf(m_run[r] - mn);
                m_run[r] = mn;
            }
#pragma unroll
            for (int tau = 0; tau < 2; ++tau)
#pragma unroll
                for (int r = 0; r < 4; ++r) {
                    float l = lg[tau][r];
                    lg[tau][r] = (l <= -1e29f) ? 0.f : __expf(l - m_run[r]);
                }
            float rsum[4];
#pragma unroll
            for (int r = 0; r < 4; ++r) rsum[r] = lg[0][r] + lg[1][r];
#pragma unroll
            for (int xm = 1; xm < 16; xm <<= 1)
#pragma unroll
                for (int r = 0; r < 4; ++r) rsum[r] += __shfl_xor(rsum[r], xm, 64);
#pragma unroll
            for (int r = 0; r < 4; ++r) l_run[r] = l_run[r] * alpha[r] + rsum[r];

#pragma unroll
            for (int th8 = 0; th8 < 8; ++th8)
#pragma unroll
                for (int r = 0; r < 4; ++r) O[th8][r] *= alpha[r];

#pragma unroll
            for (int tau = 0; tau < 2; ++tau)
#pragma unroll
                for (int r = 0; r < 4; ++r)
                    Ps[wave][quad * 4 + r][tau * 16 + lo] = f2b(lg[tau][r]);

            short8 pfrag = *(const short8*)&Ps[wave][lo][quad * 8];
#pragma unroll
            for (int th8 = 0; th8 < 8; ++th8) {
                short8 vfrag = *(const short8*)&Vt[th8 * 16 + lo][quad * 8];
                O[th8] = __builtin_amdgcn_mfma_f32_16x16x32_bf16(pfrag, vfrag, O[th8], 0, 0, 0);
            }
        }
    }

#pragma unroll
    for (int th8 = 0; th8 < 8; ++th8) {
#pragma unroll
        for (int r = 0; r < 4; ++r) {
            int t = twlo + quad * 4 + r;
            ebuf[(size_t)t * 2048 + n * 128 + th8 * 16 + lo] = f2b(O[th8][r] / l_run[r]);
        }
    }
}

// ---------------------------------------------------------------------------
extern "C" void kernel_launch(void* const* d_in, const int* in_sizes, int n_in,
                              void* d_out, int out_size, void* d_ws, size_t ws_size,
                              hipStream_t stream)
{
    const float* x   = (const float*)d_in[0];
    const int*  segp = (const int*)d_in[1];
    // d_in[2] = attn_mask (bool) -- redundant with causal+window predicate, ignored
    const float* qk  = (const float*)d_in[3];
    const float* kvk = (const float*)d_in[4];
    const float* ok  = (const float*)d_in[5];

    // Workspace (48 MB total):
    //   xb      4M bf16  (8 MB)  -- aliased by ebuf after qkv GEMM
    //   WT_qkv  8M bf16 (16 MB)  [4096][2048]
    //   WT_out  4M bf16  (8 MB)  [2048][2048]
    //   qkvb    8M bf16 (16 MB)  [2048][4096]
    bf16* xb     = (bf16*)d_ws;
    bf16* ebuf   = xb;                                  // alias (xb dead after qkv GEMM)
    bf16* WT_qkv = xb + (size_t)4 * 1024 * 1024;
    bf16* WT_out = WT_qkv + (size_t)8 * 1024 * 1024;
    bf16* qkvb   = WT_out + (size_t)4 * 1024 * 1024;
    float* outp  = (float*)d_out;

    // prep
    cvt_x_k<<<dim3(2048), dim3(256), 0, stream>>>(x, xb);
    // q_kernel (N,D,H): per n transpose (2048x128) -> WT_qkv rows n*128+h
    transpose_cvt_k<<<dim3(4, 64, 16), dim3(256), 0, stream>>>(
        qk, WT_qkv, H_DIM, D_DIM, (size_t)D_DIM * H_DIM, (size_t)H_DIM * D_DIM);
    // kv_kernel[0] (K,D,H): -> WT_qkv rows 2048 + kh*128+h
    transpose_cvt_k<<<dim3(4, 64, 8), dim3(256), 0, stream>>>(
        kvk, WT_qkv + (size_t)2048 * 2048, H_DIM, D_DIM,
        (size_t)D_DIM * H_DIM, (size_t)H_DIM * D_DIM);
    // kv_kernel[1] (K,D,H): -> WT_qkv rows 3072 + kh*128+h
    transpose_cvt_k<<<dim3(4, 64, 8), dim3(256), 0, stream>>>(
        kvk + (size_t)K_HEADS * D_DIM * H_DIM, WT_qkv + (size_t)3072 * 2048,
        H_DIM, D_DIM, (size_t)D_DIM * H_DIM, (size_t)H_DIM * D_DIM);
    // out_kernel (N,H,D): per n transpose (128x2048) -> WT_out[d][n*128+h]
    transpose_cvt_k<<<dim3(64, 4, 16), dim3(256), 0, stream>>>(
        ok, WT_out, D_DIM, D_DIM, (size_t)H_DIM * D_DIM, (size_t)H_DIM);

    // qkv projection: [2048,2048] x [4096,2048]^T -> qkvb bf16
    mfma_gemm_k<bf16><<<dim3(16, 32), dim3(256), 0, stream>>>(
        xb, WT_qkv, qkvb, 4096, 2048);
    rope_k<<<dim3(T_DIM), dim3(256), 0, stream>>>(qkvb, segp);
    attn_k<<<dim3(T_DIM / 64, N_HEADS), dim3(256), 0, stream>>>(qkvb, ebuf);
    // out projection: [2048,2048] x [2048,2048]^T -> d_out fp32
    mfma_gemm_k<float><<<dim3(16, 16), dim3(256), 0, stream>>>(
        ebuf, WT_out, outp, 2048, 2048);
}

// Round 5
// 278.301 us; speedup vs baseline: 13.1003x; 1.2268x over previous
//
#include <hip/hip_runtime.h>
#include <hip/hip_bf16.h>
#include <math.h>

// Problem constants (B=1)
#define T_DIM 2048
#define D_DIM 2048
#define N_HEADS 16
#define K_HEADS 8
#define H_DIM 128
#define WINDOW_SZ 1024
#define SOFT_CAP 50.0f
#define Q_SCALE 0.08838834764831845f   // 1/sqrt(128)
#define LN_BASE 9.210340371976184f     // ln(10000)

typedef __hip_bfloat16 bf16;
typedef __attribute__((ext_vector_type(8))) short short8;
typedef __attribute__((ext_vector_type(4))) float floatx4;

static __device__ __forceinline__ bf16 f2b(float v) { return __float2bfloat16(v); }
static __device__ __forceinline__ float b2f(bf16 v) { return __bfloat162float(v); }

// ---------------------------------------------------------------------------
// Prep 1: x fp32 -> bf16 (elementwise, 8 per thread)
// ---------------------------------------------------------------------------
__global__ __launch_bounds__(256) void cvt_x_k(const float* __restrict__ x,
                                               bf16* __restrict__ xb)
{
    const size_t i = ((size_t)blockIdx.x * 256 + threadIdx.x) * 8;
    float4 a = *(const float4*)(x + i);
    float4 b = *(const float4*)(x + i + 4);
    bf16 o[8] = {f2b(a.x), f2b(a.y), f2b(a.z), f2b(a.w),
                 f2b(b.x), f2b(b.y), f2b(b.z), f2b(b.w)};
    *(short8*)(xb + i) = *(const short8*)o;
}

// ---------------------------------------------------------------------------
// Prep 2a: all 32 (2048x128) qkv weight matrices -> WT_qkv (transposed bf16),
// one launch. z<16: q_kernel head z; z>=16: kv_kernel (c,k) = linear z-16.
// grid (4, 64, 32), block 256.
// ---------------------------------------------------------------------------
__global__ __launch_bounds__(256) void transpose_qkv_k(
    const float* __restrict__ qk, const float* __restrict__ kvk,
    bf16* __restrict__ WT)
{
    __shared__ float tile[32][33];
    const int z = blockIdx.z;
    const float* src;
    bf16* dst;
    if (z < 16) {
        src = qk + (size_t)z * D_DIM * H_DIM;
        dst = WT + (size_t)(z * 128) * 2048;
    } else {
        int m = z - 16;                       // (c*8+k) linear in kv_kernel
        src = kvk + (size_t)m * D_DIM * H_DIM;
        dst = WT + (size_t)(2048 + m * 128) * 2048;
    }
    const int tx = threadIdx.x & 31, ty = threadIdx.x >> 5;
    const int r0 = blockIdx.y * 32, c0 = blockIdx.x * 32;   // r in D, c in H
#pragma unroll
    for (int i = 0; i < 4; ++i)
        tile[ty + i * 8][tx] = src[(size_t)(r0 + ty + i * 8) * H_DIM + c0 + tx];
    __syncthreads();
#pragma unroll
    for (int i = 0; i < 4; ++i)
        dst[(size_t)(c0 + ty + i * 8) * 2048 + r0 + tx] = f2b(tile[tx][ty + i * 8]);
}

// ---------------------------------------------------------------------------
// Prep 2b: generic tiled transpose+convert (used for out_kernel).
// ---------------------------------------------------------------------------
__global__ __launch_bounds__(256) void transpose_cvt_k(
    const float* __restrict__ src, bf16* __restrict__ dst,
    int src_rstride, int dst_rstride, size_t src_mstride, size_t dst_mstride)
{
    __shared__ float tile[32][33];
    const int tx = threadIdx.x & 31, ty = threadIdx.x >> 5;
    const float* s = src + (size_t)blockIdx.z * src_mstride;
    bf16* d = dst + (size_t)blockIdx.z * dst_mstride;
    const int r0 = blockIdx.y * 32, c0 = blockIdx.x * 32;
#pragma unroll
    for (int i = 0; i < 4; ++i)
        tile[ty + i * 8][tx] = s[(size_t)(r0 + ty + i * 8) * src_rstride + c0 + tx];
    __syncthreads();
#pragma unroll
    for (int i = 0; i < 4; ++i)
        d[(size_t)(c0 + ty + i * 8) * dst_rstride + r0 + tx] = f2b(tile[tx][ty + i * 8]);
}

// ---------------------------------------------------------------------------
// MFMA GEMM (m97 structure): C[M,N] = A[M,K] * BT[N,K]^T. (round-4 verified)
// ---------------------------------------------------------------------------
template <typename CT>
__global__ __launch_bounds__(256) void mfma_gemm_k(
    const bf16* __restrict__ A, const bf16* __restrict__ BT,
    CT* __restrict__ C, int Ndim, int Kdim)
{
    __shared__ alignas(16) bf16 As[128 * 32];
    __shared__ alignas(16) bf16 Bs[128 * 32];

    const int tid  = threadIdx.x;
    const int lane = tid & 63;
    const int wave = tid >> 6;
    const int lo   = lane & 15;
    const int quad = lane >> 4;
    const int row0 = blockIdx.x * 128;
    const int col0 = blockIdx.y * 128;
    const int wm = (wave >> 1) * 64;
    const int wn = (wave & 1) * 64;

    const int lrow = lane >> 2;
    const int lcol = (lane & 3) * 8;

    floatx4 acc[4][4];
#pragma unroll
    for (int i = 0; i < 4; ++i)
#pragma unroll
        for (int j = 0; j < 4; ++j) acc[i][j] = (floatx4){0.f, 0.f, 0.f, 0.f};

    for (int k0 = 0; k0 < Kdim; k0 += 32) {
        __syncthreads();
#pragma unroll
        for (int i = 0; i < 2; ++i) {
            const int trow = wave * 32 + i * 16 + lrow;
            const bf16* ga = A  + (size_t)(row0 + trow) * Kdim + k0 + lcol;
            const bf16* gb = BT + (size_t)(col0 + trow) * Kdim + k0 + lcol;
            __builtin_amdgcn_global_load_lds(
                (const __attribute__((address_space(1))) void*)ga,
                (__attribute__((address_space(3))) void*)(As + (wave * 2 + i) * 512),
                16, 0, 0);
            __builtin_amdgcn_global_load_lds(
                (const __attribute__((address_space(1))) void*)gb,
                (__attribute__((address_space(3))) void*)(Bs + (wave * 2 + i) * 512),
                16, 0, 0);
        }
        __syncthreads();

        short8 af[4], bfr[4];
#pragma unroll
        for (int mt = 0; mt < 4; ++mt)
            af[mt] = *(const short8*)&As[(wm + mt * 16 + lo) * 32 + quad * 8];
#pragma unroll
        for (int nt = 0; nt < 4; ++nt)
            bfr[nt] = *(const short8*)&Bs[(wn + nt * 16 + lo) * 32 + quad * 8];
#pragma unroll
        for (int mt = 0; mt < 4; ++mt)
#pragma unroll
            for (int nt = 0; nt < 4; ++nt)
                acc[mt][nt] = __builtin_amdgcn_mfma_f32_16x16x32_bf16(
                    af[mt], bfr[nt], acc[mt][nt], 0, 0, 0);
    }

#pragma unroll
    for (int mt = 0; mt < 4; ++mt)
#pragma unroll
        for (int nt = 0; nt < 4; ++nt)
#pragma unroll
            for (int r = 0; r < 4; ++r) {
                int rr = row0 + wm + mt * 16 + quad * 4 + r;
                int cc = col0 + wn + nt * 16 + lo;
                float v = acc[mt][nt][r];
                if constexpr (__is_same(CT, bf16)) C[(size_t)rr * Ndim + cc] = f2b(v);
                else                               C[(size_t)rr * Ndim + cc] = v;
            }
}

// ---------------------------------------------------------------------------
// RoPE in-place on qkvb (bf16, row stride 4096). __sincosf (HW sin/cos).
// ---------------------------------------------------------------------------
__global__ __launch_bounds__(256) void rope_k(bf16* __restrict__ qkvb,
                                              const int* __restrict__ segpos)
{
    const int t = blockIdx.x;
    const float pos = (float)segpos[t];
    bf16* rowp = qkvb + (size_t)t * 4096;
    for (int p = threadIdx.x; p < 1536; p += 256) {
        bf16* buf; int hp; float scale;
        if (p < 1024) {
            hp = p & 63;
            buf = rowp + (p >> 6) * 128; scale = Q_SCALE;
        } else {
            int pp = p - 1024; hp = pp & 63;
            buf = rowp + 2048 + (pp >> 6) * 128; scale = 1.0f;
        }
        float fraction = (float)hp * (1.0f / 64.0f);
        float inv_ts = __expf(-fraction * LN_BASE);
        float ang = pos * inv_ts;
        float sv, cv; __sincosf(ang, &sv, &cv);
        float first  = b2f(buf[hp]);
        float second = b2f(buf[hp + 64]);
        buf[hp]      = f2b((first * cv - second * sv) * scale);
        buf[hp + 64] = f2b((second * cv + first * sv) * scale);
    }
}

// ---------------------------------------------------------------------------
// Flash MFMA attention, fixed-m softmax (logits bounded by softcap => m=0).
// Block: 64 q-rows x 1 head, 4 waves x 16 rows, 32-key chunks,
// single barrier per chunk, register double-buffered staging.
// ---------------------------------------------------------------------------
__global__ __launch_bounds__(256) void attn_k(
    const bf16* __restrict__ qkvb, bf16* __restrict__ ebuf)
{
    __shared__ alignas(16) bf16 Ks[2][32][136];  // [key][hd]
    __shared__ alignas(16) bf16 Vt[2][128][40];  // [hd][key]
    __shared__ alignas(16) bf16 Ps[4][16][40];   // per-wave P [row][key]

    const int t0 = blockIdx.x * 64;
    const int n  = blockIdx.y;
    const int kh = n >> 1;
    const int tid  = threadIdx.x;
    const int lane = tid & 63;
    const int wave = tid >> 6;
    const int lo   = lane & 15;
    const int quad = lane >> 4;
    const int twlo = t0 + wave * 16;

    // Q fragments (A-layout)
    short8 qf[4];
    {
        const bf16* qp = qkvb + (size_t)(twlo + lo) * 4096 + n * 128;
#pragma unroll
        for (int kc = 0; kc < 4; ++kc)
            qf[kc] = *(const short8*)(qp + kc * 32 + quad * 8);
    }

    floatx4 O[8];
#pragma unroll
    for (int i = 0; i < 8; ++i) O[i] = (floatx4){0.f, 0.f, 0.f, 0.f};
    float l_acc[4] = {0.f, 0.f, 0.f, 0.f};

    // staging thread maps
    const int key_a = tid >> 3, hd_a = (tid & 7) * 16;   // K: coalesced global + b128 LDS
    const int key_b = tid & 31, hd_b = (tid >> 5) * 16;  // V: bank-spread scatter writes

    const int s_start = (t0 > 1023) ? (t0 - 1024) : 0;   // 32-aligned
    const int nch = (t0 + 63 - s_start) / 32 + 1;

    const bf16* kg = qkvb + 2048 + kh * 128;
    const bf16* vg = qkvb + 3072 + kh * 128;

    // prefetch chunk 0
    short8 kr0 = *(const short8*)(kg + (size_t)(s_start + key_a) * 4096 + hd_a);
    short8 kr1 = *(const short8*)(kg + (size_t)(s_start + key_a) * 4096 + hd_a + 8);
    short8 vr0 = *(const short8*)(vg + (size_t)(s_start + key_b) * 4096 + hd_b);
    short8 vr1 = *(const short8*)(vg + (size_t)(s_start + key_b) * 4096 + hd_b + 8);

    for (int c = 0; c < nch; ++c) {
        const int base = s_start + c * 32;
        const int buf = c & 1;

        // write staged regs -> LDS[buf]
        *(short8*)&Ks[buf][key_a][hd_a]     = kr0;
        *(short8*)&Ks[buf][key_a][hd_a + 8] = kr1;
        {
            const bf16* v0 = (const bf16*)&vr0;
            const bf16* v1 = (const bf16*)&vr1;
#pragma unroll
            for (int i = 0; i < 8; ++i) Vt[buf][hd_b + i][key_b]     = v0[i];
#pragma unroll
            for (int i = 0; i < 8; ++i) Vt[buf][hd_b + 8 + i][key_b] = v1[i];
        }
        // prefetch chunk c+1 (in flight across the barrier)
        if (c + 1 < nch) {
            const int nb = base + 32;
            kr0 = *(const short8*)(kg + (size_t)(nb + key_a) * 4096 + hd_a);
            kr1 = *(const short8*)(kg + (size_t)(nb + key_a) * 4096 + hd_a + 8);
            vr0 = *(const short8*)(vg + (size_t)(nb + key_b) * 4096 + hd_b);
            vr1 = *(const short8*)(vg + (size_t)(nb + key_b) * 4096 + hd_b + 8);
        }
        __syncthreads();

        const int dbase = twlo - base;
        if (dbase >= -15 && dbase <= 1054) {          // wave-relevant chunk
            floatx4 S0 = (floatx4){0.f, 0.f, 0.f, 0.f};
            floatx4 S1 = (floatx4){0.f, 0.f, 0.f, 0.f};
#pragma unroll
            for (int kc = 0; kc < 4; ++kc) {
                short8 b0 = *(const short8*)&Ks[buf][lo][kc * 32 + quad * 8];
                short8 b1 = *(const short8*)&Ks[buf][16 + lo][kc * 32 + quad * 8];
                S0 = __builtin_amdgcn_mfma_f32_16x16x32_bf16(qf[kc], b0, S0, 0, 0, 0);
                S1 = __builtin_amdgcn_mfma_f32_16x16x32_bf16(qf[kc], b1, S1, 0, 0, 0);
            }
            // V fragments early (overlap lgkm with softcap VALU)
            short8 vfrag[8];
#pragma unroll
            for (int nt = 0; nt < 8; ++nt)
                vfrag[nt] = *(const short8*)&Vt[buf][nt * 16 + lo][quad * 8];

            const bool need_mask = !(dbase >= 31 && dbase <= 1008);
            const int dq = dbase + quad * 4 - lo;
            float lg[2][4];
#pragma unroll
            for (int tau = 0; tau < 2; ++tau) {
#pragma unroll
                for (int r = 0; r < 4; ++r) {
                    float sv = (tau == 0) ? S0[r] : S1[r];
                    float ax = fabsf(sv) * (2.0f / SOFT_CAP);
                    float e2 = __expf(-ax);
                    float th = (1.0f - e2) * __builtin_amdgcn_rcpf(1.0f + e2);
                    float l  = copysignf(SOFT_CAP * th, sv);
                    float p  = __expf(l);                 // fixed m=0; l in [-50,50]
                    if (need_mask) {
                        int d = dq + r - tau * 16;        // t_idx - s_idx
                        if ((unsigned)d > 1023u) p = 0.f;
                    }
                    lg[tau][r] = p;
                }
            }
#pragma unroll
            for (int r = 0; r < 4; ++r) l_acc[r] += lg[0][r] + lg[1][r];

            // P -> LDS (C-layout scatter), read back A-layout (wave-local)
#pragma unroll
            for (int tau = 0; tau < 2; ++tau)
#pragma unroll
                for (int r = 0; r < 4; ++r)
                    Ps[wave][quad * 4 + r][tau * 16 + lo] = f2b(lg[tau][r]);

            short8 pfrag = *(const short8*)&Ps[wave][lo][quad * 8];
#pragma unroll
            for (int nt = 0; nt < 8; ++nt)
                O[nt] = __builtin_amdgcn_mfma_f32_16x16x32_bf16(pfrag, vfrag[nt], O[nt], 0, 0, 0);
        }
    }

    // ---- one final row-sum reduction + normalize + store ----
#pragma unroll
    for (int xm = 1; xm < 16; xm <<= 1)
#pragma unroll
        for (int r = 0; r < 4; ++r) l_acc[r] += __shfl_xor(l_acc[r], xm, 64);
    float invl[4];
#pragma unroll
    for (int r = 0; r < 4; ++r) invl[r] = 1.0f / l_acc[r];

#pragma unroll
    for (int nt = 0; nt < 8; ++nt)
#pragma unroll
        for (int r = 0; r < 4; ++r) {
            int t = twlo + quad * 4 + r;
            ebuf[(size_t)t * 2048 + n * 128 + nt * 16 + lo] = f2b(O[nt][r] * invl[r]);
        }
}

// ---------------------------------------------------------------------------
extern "C" void kernel_launch(void* const* d_in, const int* in_sizes, int n_in,
                              void* d_out, int out_size, void* d_ws, size_t ws_size,
                              hipStream_t stream)
{
    const float* x   = (const float*)d_in[0];
    const int*  segp = (const int*)d_in[1];
    // d_in[2] = attn_mask (bool) -- redundant with causal+window predicate, ignored
    const float* qk  = (const float*)d_in[3];
    const float* kvk = (const float*)d_in[4];
    const float* ok  = (const float*)d_in[5];

    // Workspace (48 MB total):
    //   xb      4M bf16  (8 MB)  -- aliased by ebuf after qkv GEMM
    //   WT_qkv  8M bf16 (16 MB)  [4096][2048]
    //   WT_out  4M bf16  (8 MB)  [2048][2048]
    //   qkvb    8M bf16 (16 MB)  [2048][4096]
    bf16* xb     = (bf16*)d_ws;
    bf16* ebuf   = xb;                                  // alias (xb dead after qkv GEMM)
    bf16* WT_qkv = xb + (size_t)4 * 1024 * 1024;
    bf16* WT_out = WT_qkv + (size_t)8 * 1024 * 1024;
    bf16* qkvb   = WT_out + (size_t)4 * 1024 * 1024;
    float* outp  = (float*)d_out;

    cvt_x_k<<<dim3(2048), dim3(256), 0, stream>>>(x, xb);
    transpose_qkv_k<<<dim3(4, 64, 32), dim3(256), 0, stream>>>(qk, kvk, WT_qkv);
    transpose_cvt_k<<<dim3(64, 4, 16), dim3(256), 0, stream>>>(
        ok, WT_out, D_DIM, D_DIM, (size_t)H_DIM * D_DIM, (size_t)H_DIM);

    mfma_gemm_k<bf16><<<dim3(16, 32), dim3(256), 0, stream>>>(
        xb, WT_qkv, qkvb, 4096, 2048);
    rope_k<<<dim3(T_DIM), dim3(256), 0, stream>>>(qkvb, segp);
    attn_k<<<dim3(T_DIM / 64, N_HEADS), dim3(256), 0, stream>>>(qkvb, ebuf);
    mfma_gemm_k<float><<<dim3(16, 16), dim3(256), 0, stream>>>(
        ebuf, WT_out, outp, 2048, 2048);
}

// Round 6
// 265.235 us; speedup vs baseline: 13.7456x; 1.0493x over previous
//
#include <hip/hip_runtime.h>
#include <hip/hip_bf16.h>
#include <math.h>

// Problem constants (B=1)
#define T_DIM 2048
#define D_DIM 2048
#define N_HEADS 16
#define K_HEADS 8
#define H_DIM 128
#define WINDOW_SZ 1024
#define SOFT_CAP 50.0f
#define Q_SCALE 0.08838834764831845f   // 1/sqrt(128)
#define LN_BASE 9.210340371976184f     // ln(10000)

typedef __hip_bfloat16 bf16;
typedef __attribute__((ext_vector_type(8))) short short8;
typedef __attribute__((ext_vector_type(4))) float floatx4;

static __device__ __forceinline__ bf16 f2b(float v) { return __float2bfloat16(v); }
static __device__ __forceinline__ float b2f(bf16 v) { return __bfloat162float(v); }

// ---------------------------------------------------------------------------
// Fused prep: 1D grid.
//   [0, 8192)     : qkv weight transpose (32 matrices, 2048x128 -> rows z*128 of WT_qkv)
//   [8192, 12288) : out weight transpose (16 matrices, 128x2048 -> cols z*128 of WT_out)
//   [12288,14336) : x fp32 -> bf16 copy
// ---------------------------------------------------------------------------
__global__ __launch_bounds__(256) void prep_k(
    const float* __restrict__ x, const float* __restrict__ qk,
    const float* __restrict__ kvk, const float* __restrict__ ok,
    bf16* __restrict__ xb, bf16* __restrict__ WT_qkv, bf16* __restrict__ WT_out)
{
    __shared__ float tile[32][33];
    const int b = blockIdx.x;
    const int tid = threadIdx.x;
    const int tx = tid & 31, ty = tid >> 5;

    if (b < 8192) {
        const int z = b >> 8, rem = b & 255;
        const int c0 = (rem & 3) * 32;        // over H (128)
        const int r0 = (rem >> 2) * 32;       // over D (2048)
        const float* src = (z < 16) ? qk + (size_t)z * D_DIM * H_DIM
                                    : kvk + (size_t)(z - 16) * D_DIM * H_DIM;
        bf16* dst = WT_qkv + (size_t)z * 128 * 2048;   // rows z*128 (q and kv contiguous)
#pragma unroll
        for (int i = 0; i < 4; ++i)
            tile[ty + i * 8][tx] = src[(size_t)(r0 + ty + i * 8) * H_DIM + c0 + tx];
        __syncthreads();
#pragma unroll
        for (int i = 0; i < 4; ++i)
            dst[(size_t)(c0 + ty + i * 8) * 2048 + r0 + tx] = f2b(tile[tx][ty + i * 8]);
    } else if (b < 12288) {
        const int b2 = b - 8192;
        const int z = b2 >> 8, rem = b2 & 255;
        const int c0 = (rem & 63) * 32;       // over D (2048)
        const int r0 = (rem >> 6) * 32;       // over H (128)
        const float* src = ok + (size_t)z * H_DIM * D_DIM;
        bf16* dst = WT_out + (size_t)z * H_DIM;        // column block n*128
#pragma unroll
        for (int i = 0; i < 4; ++i)
            tile[ty + i * 8][tx] = src[(size_t)(r0 + ty + i * 8) * D_DIM + c0 + tx];
        __syncthreads();
#pragma unroll
        for (int i = 0; i < 4; ++i)
            dst[(size_t)(c0 + ty + i * 8) * 2048 + r0 + tx] = f2b(tile[tx][ty + i * 8]);
    } else {
        const size_t i = ((size_t)(b - 12288) * 256 + tid) * 8;
        float4 a = *(const float4*)(x + i);
        float4 bb = *(const float4*)(x + i + 4);
        bf16 o[8] = {f2b(a.x), f2b(a.y), f2b(a.z), f2b(a.w),
                     f2b(bb.x), f2b(bb.y), f2b(bb.z), f2b(bb.w)};
        *(short8*)(xb + i) = *(const short8*)o;
    }
}

// ---------------------------------------------------------------------------
// MFMA GEMM (m97 structure + XOR-swizzled LDS): C[M,N] = A[M,K] * BT[N,K]^T.
// 128x128 tile, BK=32, 4 waves 2x2, 4x4 mfma_f32_16x16x32_bf16 per wave.
// LDS layout: row r (64 B) holds its four 16B chunks at slot c ^ ((r>>1)&3)
// -> both lds-dma writes (lane-contiguous) and b128 reads are conflict-free.
// ---------------------------------------------------------------------------
template <typename CT>
__global__ __launch_bounds__(256) void mfma_gemm_k(
    const bf16* __restrict__ A, const bf16* __restrict__ BT,
    CT* __restrict__ C, int Ndim, int Kdim)
{
    __shared__ alignas(16) bf16 As[128 * 32];
    __shared__ alignas(16) bf16 Bs[128 * 32];

    const int tid  = threadIdx.x;
    const int lane = tid & 63;
    const int wave = tid >> 6;
    const int lo   = lane & 15;
    const int quad = lane >> 4;
    const int row0 = blockIdx.x * 128;
    const int col0 = blockIdx.y * 128;
    const int wm = (wave >> 1) * 64;
    const int wn = (wave & 1) * 64;

    const int lrow = lane >> 2;
    const int lcol = ((lane & 3) ^ ((lane >> 3) & 3)) * 8;   // swizzled source chunk
    const int swk  = (quad ^ ((lo >> 1) & 3)) * 8;           // swizzled read chunk

    floatx4 acc[4][4];
#pragma unroll
    for (int i = 0; i < 4; ++i)
#pragma unroll
        for (int j = 0; j < 4; ++j) acc[i][j] = (floatx4){0.f, 0.f, 0.f, 0.f};

    for (int k0 = 0; k0 < Kdim; k0 += 32) {
        __syncthreads();
#pragma unroll
        for (int i = 0; i < 2; ++i) {
            const int trow = wave * 32 + i * 16 + lrow;
            const bf16* ga = A  + (size_t)(row0 + trow) * Kdim + k0 + lcol;
            const bf16* gb = BT + (size_t)(col0 + trow) * Kdim + k0 + lcol;
            __builtin_amdgcn_global_load_lds(
                (const __attribute__((address_space(1))) void*)ga,
                (__attribute__((address_space(3))) void*)(As + (wave * 2 + i) * 512),
                16, 0, 0);
            __builtin_amdgcn_global_load_lds(
                (const __attribute__((address_space(1))) void*)gb,
                (__attribute__((address_space(3))) void*)(Bs + (wave * 2 + i) * 512),
                16, 0, 0);
        }
        __syncthreads();

        short8 af[4], bfr[4];
#pragma unroll
        for (int mt = 0; mt < 4; ++mt)
            af[mt] = *(const short8*)&As[(wm + mt * 16 + lo) * 32 + swk];
#pragma unroll
        for (int nt = 0; nt < 4; ++nt)
            bfr[nt] = *(const short8*)&Bs[(wn + nt * 16 + lo) * 32 + swk];
#pragma unroll
        for (int mt = 0; mt < 4; ++mt)
#pragma unroll
            for (int nt = 0; nt < 4; ++nt)
                acc[mt][nt] = __builtin_amdgcn_mfma_f32_16x16x32_bf16(
                    af[mt], bfr[nt], acc[mt][nt], 0, 0, 0);
    }

#pragma unroll
    for (int mt = 0; mt < 4; ++mt)
#pragma unroll
        for (int nt = 0; nt < 4; ++nt)
#pragma unroll
            for (int r = 0; r < 4; ++r) {
                int rr = row0 + wm + mt * 16 + quad * 4 + r;
                int cc = col0 + wn + nt * 16 + lo;
                float v = acc[mt][nt][r];
                if constexpr (__is_same(CT, bf16)) C[(size_t)rr * Ndim + cc] = f2b(v);
                else                               C[(size_t)rr * Ndim + cc] = v;
            }
}

// ---------------------------------------------------------------------------
// RoPE on K only (q-rope fused into attn). 512 pairs per t.
// ---------------------------------------------------------------------------
__global__ __launch_bounds__(256) void rope_kk(bf16* __restrict__ qkvb,
                                               const int* __restrict__ segpos)
{
    const int t = blockIdx.x;
    const float pos = (float)segpos[t];
    bf16* rowp = qkvb + (size_t)t * 4096 + 2048;
#pragma unroll
    for (int it = 0; it < 2; ++it) {
        int p = threadIdx.x + it * 256;
        int hp = p & 63;
        bf16* buf = rowp + (p >> 6) * 128;
        float fraction = (float)hp * (1.0f / 64.0f);
        float inv_ts = __expf(-fraction * LN_BASE);
        float ang = pos * inv_ts;
        float sv, cv; __sincosf(ang, &sv, &cv);
        float first  = b2f(buf[hp]);
        float second = b2f(buf[hp + 64]);
        buf[hp]      = f2b(first * cv - second * sv);
        buf[hp + 64] = f2b(second * cv + first * sv);
    }
}

// ---------------------------------------------------------------------------
// Flash MFMA attention, fixed-m softmax (softcap bounds logits to ±50).
// Q-rope fused into the Q-fragment load (pairs are register-local: qf[kc]/qf[kc+2]).
// V staged via paired-key packed b32 writes (2 keys/thread), Vt stride 40.
// ---------------------------------------------------------------------------
__global__ __launch_bounds__(256) void attn_k(
    const bf16* __restrict__ qkvb, const int* __restrict__ segpos,
    bf16* __restrict__ ebuf)
{
    __shared__ alignas(16) bf16 Ks[2][32][136];  // [key][hd]
    __shared__ alignas(16) bf16 Vt[2][128][40];  // [hd][key] (stride 80 B: 16B-aligned rows)
    __shared__ alignas(16) bf16 Ps[4][16][40];   // per-wave P [row][key]

    const int t0 = blockIdx.x * 64;
    const int n  = blockIdx.y;
    const int kh = n >> 1;
    const int tid  = threadIdx.x;
    const int lane = tid & 63;
    const int wave = tid >> 6;
    const int lo   = lane & 15;
    const int quad = lane >> 4;
    const int twlo = t0 + wave * 16;

    // ---- Q fragments with fused RoPE + Q_SCALE ----
    short8 qf[4];
    {
        const int tq = twlo + lo;
        const float pos = (float)segpos[tq];
        const bf16* qp = qkvb + (size_t)tq * 4096 + n * 128;
        float qv[4][8];
#pragma unroll
        for (int kc = 0; kc < 4; ++kc) {
            short8 raw = *(const short8*)(qp + kc * 32 + quad * 8);
            const bf16* rb = (const bf16*)&raw;
#pragma unroll
            for (int j = 0; j < 8; ++j) qv[kc][j] = b2f(rb[j]);
        }
#pragma unroll
        for (int kc = 0; kc < 2; ++kc)
#pragma unroll
            for (int j = 0; j < 8; ++j) {
                int hp = kc * 32 + quad * 8 + j;
                float ang = pos * __expf(-(float)hp * (1.0f / 64.0f) * LN_BASE);
                float sv, cv; __sincosf(ang, &sv, &cv);
                float first = qv[kc][j], second = qv[kc + 2][j];
                qv[kc][j]     = (first * cv - second * sv) * Q_SCALE;
                qv[kc + 2][j] = (second * cv + first * sv) * Q_SCALE;
            }
#pragma unroll
        for (int kc = 0; kc < 4; ++kc) {
            bf16 o[8];
#pragma unroll
            for (int j = 0; j < 8; ++j) o[j] = f2b(qv[kc][j]);
            qf[kc] = *(const short8*)o;
        }
    }

    floatx4 O[8];
#pragma unroll
    for (int i = 0; i < 8; ++i) O[i] = (floatx4){0.f, 0.f, 0.f, 0.f};
    float l_acc[4] = {0.f, 0.f, 0.f, 0.f};

    // staging maps
    const int key_a = tid >> 3,      hd_a = (tid & 7) * 16;   // K
    const int kp2   = (tid & 15) * 2, hd_b = (tid >> 4) * 8;  // V (2 keys x 8 hd)

    const int s_start = (t0 > 1023) ? (t0 - 1024) : 0;        // 32-aligned
    const int nch = (t0 + 63 - s_start) / 32 + 1;

    const bf16* kg = qkvb + 2048 + kh * 128;
    const bf16* vg = qkvb + 3072 + kh * 128;

    // prefetch chunk 0
    short8 kr0 = *(const short8*)(kg + (size_t)(s_start + key_a) * 4096 + hd_a);
    short8 kr1 = *(const short8*)(kg + (size_t)(s_start + key_a) * 4096 + hd_a + 8);
    short8 vr0 = *(const short8*)(vg + (size_t)(s_start + kp2) * 4096 + hd_b);
    short8 vr1 = *(const short8*)(vg + (size_t)(s_start + kp2 + 1) * 4096 + hd_b);

    for (int c = 0; c < nch; ++c) {
        const int base = s_start + c * 32;
        const int buf = c & 1;

        *(short8*)&Ks[buf][key_a][hd_a]     = kr0;
        *(short8*)&Ks[buf][key_a][hd_a + 8] = kr1;
#pragma unroll
        for (int i = 0; i < 8; ++i) {
            unsigned pk = (unsigned)(unsigned short)vr0[i] |
                          ((unsigned)(unsigned short)vr1[i] << 16);
            *(unsigned*)&Vt[buf][hd_b + i][kp2] = pk;
        }
        if (c + 1 < nch) {
            const int nb = base + 32;
            kr0 = *(const short8*)(kg + (size_t)(nb + key_a) * 4096 + hd_a);
            kr1 = *(const short8*)(kg + (size_t)(nb + key_a) * 4096 + hd_a + 8);
            vr0 = *(const short8*)(vg + (size_t)(nb + kp2) * 4096 + hd_b);
            vr1 = *(const short8*)(vg + (size_t)(nb + kp2 + 1) * 4096 + hd_b);
        }
        __syncthreads();

        const int dbase = twlo - base;
        if (dbase >= -15 && dbase <= 1054) {
            floatx4 S0 = (floatx4){0.f, 0.f, 0.f, 0.f};
            floatx4 S1 = (floatx4){0.f, 0.f, 0.f, 0.f};
#pragma unroll
            for (int kc = 0; kc < 4; ++kc) {
                short8 b0 = *(const short8*)&Ks[buf][lo][kc * 32 + quad * 8];
                short8 b1 = *(const short8*)&Ks[buf][16 + lo][kc * 32 + quad * 8];
                S0 = __builtin_amdgcn_mfma_f32_16x16x32_bf16(qf[kc], b0, S0, 0, 0, 0);
                S1 = __builtin_amdgcn_mfma_f32_16x16x32_bf16(qf[kc], b1, S1, 0, 0, 0);
            }
            short8 vfrag[8];
#pragma unroll
            for (int nt = 0; nt < 8; ++nt)
                vfrag[nt] = *(const short8*)&Vt[buf][nt * 16 + lo][quad * 8];

            const bool need_mask = !(dbase >= 31 && dbase <= 1008);
            const int dq = dbase + quad * 4 - lo;
            float lg[2][4];
#pragma unroll
            for (int tau = 0; tau < 2; ++tau) {
#pragma unroll
                for (int r = 0; r < 4; ++r) {
                    float sv = (tau == 0) ? S0[r] : S1[r];
                    float ax = fabsf(sv) * (2.0f / SOFT_CAP);
                    float e2 = __expf(-ax);
                    float th = (1.0f - e2) * __builtin_amdgcn_rcpf(1.0f + e2);
                    float l  = copysignf(SOFT_CAP * th, sv);
                    float p  = __expf(l);                 // fixed m=0
                    if (need_mask) {
                        int d = dq + r - tau * 16;        // t_idx - s_idx
                        if ((unsigned)d > 1023u) p = 0.f;
                    }
                    lg[tau][r] = p;
                }
            }
#pragma unroll
            for (int r = 0; r < 4; ++r) l_acc[r] += lg[0][r] + lg[1][r];

#pragma unroll
            for (int tau = 0; tau < 2; ++tau)
#pragma unroll
                for (int r = 0; r < 4; ++r)
                    Ps[wave][quad * 4 + r][tau * 16 + lo] = f2b(lg[tau][r]);

            short8 pfrag = *(const short8*)&Ps[wave][lo][quad * 8];
#pragma unroll
            for (int nt = 0; nt < 8; ++nt)
                O[nt] = __builtin_amdgcn_mfma_f32_16x16x32_bf16(pfrag, vfrag[nt], O[nt], 0, 0, 0);
        }
    }

#pragma unroll
    for (int xm = 1; xm < 16; xm <<= 1)
#pragma unroll
        for (int r = 0; r < 4; ++r) l_acc[r] += __shfl_xor(l_acc[r], xm, 64);
    float invl[4];
#pragma unroll
    for (int r = 0; r < 4; ++r) invl[r] = 1.0f / l_acc[r];

#pragma unroll
    for (int nt = 0; nt < 8; ++nt)
#pragma unroll
        for (int r = 0; r < 4; ++r) {
            int t = twlo + quad * 4 + r;
            ebuf[(size_t)t * 2048 + n * 128 + nt * 16 + lo] = f2b(O[nt][r] * invl[r]);
        }
}

// ---------------------------------------------------------------------------
extern "C" void kernel_launch(void* const* d_in, const int* in_sizes, int n_in,
                              void* d_out, int out_size, void* d_ws, size_t ws_size,
                              hipStream_t stream)
{
    const float* x   = (const float*)d_in[0];
    const int*  segp = (const int*)d_in[1];
    // d_in[2] = attn_mask (bool) -- redundant with causal+window predicate, ignored
    const float* qk  = (const float*)d_in[3];
    const float* kvk = (const float*)d_in[4];
    const float* ok  = (const float*)d_in[5];

    // Workspace (48 MB): xb(8MB, aliased by ebuf) | WT_qkv(16MB) | WT_out(8MB) | qkvb(16MB)
    bf16* xb     = (bf16*)d_ws;
    bf16* ebuf   = xb;
    bf16* WT_qkv = xb + (size_t)4 * 1024 * 1024;
    bf16* WT_out = WT_qkv + (size_t)8 * 1024 * 1024;
    bf16* qkvb   = WT_out + (size_t)4 * 1024 * 1024;
    float* outp  = (float*)d_out;

    prep_k<<<dim3(14336), dim3(256), 0, stream>>>(x, qk, kvk, ok, xb, WT_qkv, WT_out);
    mfma_gemm_k<bf16><<<dim3(16, 32), dim3(256), 0, stream>>>(
        xb, WT_qkv, qkvb, 4096, 2048);
    rope_kk<<<dim3(T_DIM), dim3(256), 0, stream>>>(qkvb, segp);
    attn_k<<<dim3(T_DIM / 64, N_HEADS), dim3(256), 0, stream>>>(qkvb, segp, ebuf);
    mfma_gemm_k<float><<<dim3(16, 16), dim3(256), 0, stream>>>(
        ebuf, WT_out, outp, 2048, 2048);
}

// Round 7
// 257.903 us; speedup vs baseline: 14.1364x; 1.0284x over previous
//
#include <hip/hip_runtime.h>
#include <hip/hip_bf16.h>
#include <math.h>

// Problem constants (B=1)
#define T_DIM 2048
#define D_DIM 2048
#define N_HEADS 16
#define K_HEADS 8
#define H_DIM 128
#define WINDOW_SZ 1024
#define SOFT_CAP 50.0f
#define Q_SCALE 0.08838834764831845f   // 1/sqrt(128)
#define LN_BASE 9.210340371976184f     // ln(10000)

typedef __hip_bfloat16 bf16;
typedef __attribute__((ext_vector_type(8))) short short8;
typedef __attribute__((ext_vector_type(4))) float floatx4;

static __device__ __forceinline__ bf16 f2b(float v) { return __float2bfloat16(v); }
static __device__ __forceinline__ float b2f(bf16 v) { return __bfloat162float(v); }

// ---------------------------------------------------------------------------
// Fused prep: 1D grid.
//   [0, 8192)     : qkv weight transpose (32 matrices, 2048x128 -> rows z*128 of WT_qkv)
//   [8192, 12288) : out weight transpose (16 matrices, 128x2048 -> cols z*128 of WT_out)
//   [12288,14336) : x fp32 -> bf16 copy
// ---------------------------------------------------------------------------
__global__ __launch_bounds__(256) void prep_k(
    const float* __restrict__ x, const float* __restrict__ qk,
    const float* __restrict__ kvk, const float* __restrict__ ok,
    bf16* __restrict__ xb, bf16* __restrict__ WT_qkv, bf16* __restrict__ WT_out)
{
    __shared__ float tile[32][33];
    const int b = blockIdx.x;
    const int tid = threadIdx.x;
    const int tx = tid & 31, ty = tid >> 5;

    if (b < 8192) {
        const int z = b >> 8, rem = b & 255;
        const int c0 = (rem & 3) * 32;        // over H (128)
        const int r0 = (rem >> 2) * 32;       // over D (2048)
        const float* src = (z < 16) ? qk + (size_t)z * D_DIM * H_DIM
                                    : kvk + (size_t)(z - 16) * D_DIM * H_DIM;
        bf16* dst = WT_qkv + (size_t)z * 128 * 2048;
#pragma unroll
        for (int i = 0; i < 4; ++i)
            tile[ty + i * 8][tx] = src[(size_t)(r0 + ty + i * 8) * H_DIM + c0 + tx];
        __syncthreads();
#pragma unroll
        for (int i = 0; i < 4; ++i)
            dst[(size_t)(c0 + ty + i * 8) * 2048 + r0 + tx] = f2b(tile[tx][ty + i * 8]);
    } else if (b < 12288) {
        const int b2 = b - 8192;
        const int z = b2 >> 8, rem = b2 & 255;
        const int c0 = (rem & 63) * 32;       // over D (2048)
        const int r0 = (rem >> 6) * 32;       // over H (128)
        const float* src = ok + (size_t)z * H_DIM * D_DIM;
        bf16* dst = WT_out + (size_t)z * H_DIM;
#pragma unroll
        for (int i = 0; i < 4; ++i)
            tile[ty + i * 8][tx] = src[(size_t)(r0 + ty + i * 8) * D_DIM + c0 + tx];
        __syncthreads();
#pragma unroll
        for (int i = 0; i < 4; ++i)
            dst[(size_t)(c0 + ty + i * 8) * 2048 + r0 + tx] = f2b(tile[tx][ty + i * 8]);
    } else {
        const size_t i = ((size_t)(b - 12288) * 256 + tid) * 8;
        float4 a = *(const float4*)(x + i);
        float4 bb = *(const float4*)(x + i + 4);
        bf16 o[8] = {f2b(a.x), f2b(a.y), f2b(a.z), f2b(a.w),
                     f2b(bb.x), f2b(bb.y), f2b(bb.z), f2b(bb.w)};
        *(short8*)(xb + i) = *(const short8*)o;
    }
}

// ---------------------------------------------------------------------------
// MFMA GEMM (m97 structure + XOR-swizzled LDS): C[M,N] = A[M,K] * BT[N,K]^T.
// 128x128 tile, BK=32, 4 waves 2x2, 4x4 mfma_f32_16x16x32_bf16 per wave.
// ---------------------------------------------------------------------------
template <typename CT>
__global__ __launch_bounds__(256) void mfma_gemm_k(
    const bf16* __restrict__ A, const bf16* __restrict__ BT,
    CT* __restrict__ C, int Ndim, int Kdim)
{
    __shared__ alignas(16) bf16 As[128 * 32];
    __shared__ alignas(16) bf16 Bs[128 * 32];

    const int tid  = threadIdx.x;
    const int lane = tid & 63;
    const int wave = tid >> 6;
    const int lo   = lane & 15;
    const int quad = lane >> 4;
    const int row0 = blockIdx.x * 128;
    const int col0 = blockIdx.y * 128;
    const int wm = (wave >> 1) * 64;
    const int wn = (wave & 1) * 64;

    const int lrow = lane >> 2;
    const int lcol = ((lane & 3) ^ ((lane >> 3) & 3)) * 8;
    const int swk  = (quad ^ ((lo >> 1) & 3)) * 8;

    floatx4 acc[4][4];
#pragma unroll
    for (int i = 0; i < 4; ++i)
#pragma unroll
        for (int j = 0; j < 4; ++j) acc[i][j] = (floatx4){0.f, 0.f, 0.f, 0.f};

    for (int k0 = 0; k0 < Kdim; k0 += 32) {
        __syncthreads();
#pragma unroll
        for (int i = 0; i < 2; ++i) {
            const int trow = wave * 32 + i * 16 + lrow;
            const bf16* ga = A  + (size_t)(row0 + trow) * Kdim + k0 + lcol;
            const bf16* gb = BT + (size_t)(col0 + trow) * Kdim + k0 + lcol;
            __builtin_amdgcn_global_load_lds(
                (const __attribute__((address_space(1))) void*)ga,
                (__attribute__((address_space(3))) void*)(As + (wave * 2 + i) * 512),
                16, 0, 0);
            __builtin_amdgcn_global_load_lds(
                (const __attribute__((address_space(1))) void*)gb,
                (__attribute__((address_space(3))) void*)(Bs + (wave * 2 + i) * 512),
                16, 0, 0);
        }
        __syncthreads();

        short8 af[4], bfr[4];
#pragma unroll
        for (int mt = 0; mt < 4; ++mt)
            af[mt] = *(const short8*)&As[(wm + mt * 16 + lo) * 32 + swk];
#pragma unroll
        for (int nt = 0; nt < 4; ++nt)
            bfr[nt] = *(const short8*)&Bs[(wn + nt * 16 + lo) * 32 + swk];
#pragma unroll
        for (int mt = 0; mt < 4; ++mt)
#pragma unroll
            for (int nt = 0; nt < 4; ++nt)
                acc[mt][nt] = __builtin_amdgcn_mfma_f32_16x16x32_bf16(
                    af[mt], bfr[nt], acc[mt][nt], 0, 0, 0);
    }

#pragma unroll
    for (int mt = 0; mt < 4; ++mt)
#pragma unroll
        for (int nt = 0; nt < 4; ++nt)
#pragma unroll
            for (int r = 0; r < 4; ++r) {
                int rr = row0 + wm + mt * 16 + quad * 4 + r;
                int cc = col0 + wn + nt * 16 + lo;
                float v = acc[mt][nt][r];
                if constexpr (__is_same(CT, bf16)) C[(size_t)rr * Ndim + cc] = f2b(v);
                else                               C[(size_t)rr * Ndim + cc] = v;
            }
}

// ---------------------------------------------------------------------------
// Split-K MFMA GEMM: grid.z selects K-half; writes fp32 partials.
// Same tile structure as mfma_gemm_k; Ndim=2048, K-half = 1024.
// ---------------------------------------------------------------------------
__global__ __launch_bounds__(256) void mfma_gemm_splitk_k(
    const bf16* __restrict__ A, const bf16* __restrict__ BT,
    float* __restrict__ P0, float* __restrict__ P1)
{
    __shared__ alignas(16) bf16 As[128 * 32];
    __shared__ alignas(16) bf16 Bs[128 * 32];

    const int tid  = threadIdx.x;
    const int lane = tid & 63;
    const int wave = tid >> 6;
    const int lo   = lane & 15;
    const int quad = lane >> 4;
    const int row0 = blockIdx.x * 128;
    const int col0 = blockIdx.y * 128;
    const int kbeg = blockIdx.z * 1024;
    float* __restrict__ P = blockIdx.z ? P1 : P0;
    const int wm = (wave >> 1) * 64;
    const int wn = (wave & 1) * 64;

    const int lrow = lane >> 2;
    const int lcol = ((lane & 3) ^ ((lane >> 3) & 3)) * 8;
    const int swk  = (quad ^ ((lo >> 1) & 3)) * 8;

    floatx4 acc[4][4];
#pragma unroll
    for (int i = 0; i < 4; ++i)
#pragma unroll
        for (int j = 0; j < 4; ++j) acc[i][j] = (floatx4){0.f, 0.f, 0.f, 0.f};

    for (int k0 = kbeg; k0 < kbeg + 1024; k0 += 32) {
        __syncthreads();
#pragma unroll
        for (int i = 0; i < 2; ++i) {
            const int trow = wave * 32 + i * 16 + lrow;
            const bf16* ga = A  + (size_t)(row0 + trow) * 2048 + k0 + lcol;
            const bf16* gb = BT + (size_t)(col0 + trow) * 2048 + k0 + lcol;
            __builtin_amdgcn_global_load_lds(
                (const __attribute__((address_space(1))) void*)ga,
                (__attribute__((address_space(3))) void*)(As + (wave * 2 + i) * 512),
                16, 0, 0);
            __builtin_amdgcn_global_load_lds(
                (const __attribute__((address_space(1))) void*)gb,
                (__attribute__((address_space(3))) void*)(Bs + (wave * 2 + i) * 512),
                16, 0, 0);
        }
        __syncthreads();

        short8 af[4], bfr[4];
#pragma unroll
        for (int mt = 0; mt < 4; ++mt)
            af[mt] = *(const short8*)&As[(wm + mt * 16 + lo) * 32 + swk];
#pragma unroll
        for (int nt = 0; nt < 4; ++nt)
            bfr[nt] = *(const short8*)&Bs[(wn + nt * 16 + lo) * 32 + swk];
#pragma unroll
        for (int mt = 0; mt < 4; ++mt)
#pragma unroll
            for (int nt = 0; nt < 4; ++nt)
                acc[mt][nt] = __builtin_amdgcn_mfma_f32_16x16x32_bf16(
                    af[mt], bfr[nt], acc[mt][nt], 0, 0, 0);
    }

#pragma unroll
    for (int mt = 0; mt < 4; ++mt)
#pragma unroll
        for (int nt = 0; nt < 4; ++nt)
#pragma unroll
            for (int r = 0; r < 4; ++r) {
                int rr = row0 + wm + mt * 16 + quad * 4 + r;
                int cc = col0 + wn + nt * 16 + lo;
                P[(size_t)rr * 2048 + cc] = acc[mt][nt][r];
            }
}

// ---------------------------------------------------------------------------
// out = P0 + P1 (float4, 4 elems/thread)
// ---------------------------------------------------------------------------
__global__ __launch_bounds__(256) void add_out_k(
    const float* __restrict__ P0, const float* __restrict__ P1,
    float* __restrict__ out)
{
    const size_t i = ((size_t)blockIdx.x * 256 + threadIdx.x) * 4;
    float4 a = *(const float4*)(P0 + i);
    float4 b = *(const float4*)(P1 + i);
    float4 o = {a.x + b.x, a.y + b.y, a.z + b.z, a.w + b.w};
    *(float4*)(out + i) = o;
}

// ---------------------------------------------------------------------------
// RoPE on K only (q-rope fused into attn). 512 pairs per t.
// ---------------------------------------------------------------------------
__global__ __launch_bounds__(256) void rope_kk(bf16* __restrict__ qkvb,
                                               const int* __restrict__ segpos)
{
    const int t = blockIdx.x;
    const float pos = (float)segpos[t];
    bf16* rowp = qkvb + (size_t)t * 4096 + 2048;
#pragma unroll
    for (int it = 0; it < 2; ++it) {
        int p = threadIdx.x + it * 256;
        int hp = p & 63;
        bf16* buf = rowp + (p >> 6) * 128;
        float fraction = (float)hp * (1.0f / 64.0f);
        float inv_ts = __expf(-fraction * LN_BASE);
        float ang = pos * inv_ts;
        float sv, cv; __sincosf(ang, &sv, &cv);
        float first  = b2f(buf[hp]);
        float second = b2f(buf[hp + 64]);
        buf[hp]      = f2b(first * cv - second * sv);
        buf[hp + 64] = f2b(second * cv + first * sv);
    }
}

// ---------------------------------------------------------------------------
// Flash MFMA attention, fixed-m softmax (softcap bounds logits to ±50).
// Q-rope fused into the Q-fragment load. (round-6 verified)
// ---------------------------------------------------------------------------
__global__ __launch_bounds__(256) void attn_k(
    const bf16* __restrict__ qkvb, const int* __restrict__ segpos,
    bf16* __restrict__ ebuf)
{
    __shared__ alignas(16) bf16 Ks[2][32][136];
    __shared__ alignas(16) bf16 Vt[2][128][40];
    __shared__ alignas(16) bf16 Ps[4][16][40];

    const int t0 = blockIdx.x * 64;
    const int n  = blockIdx.y;
    const int kh = n >> 1;
    const int tid  = threadIdx.x;
    const int lane = tid & 63;
    const int wave = tid >> 6;
    const int lo   = lane & 15;
    const int quad = lane >> 4;
    const int twlo = t0 + wave * 16;

    short8 qf[4];
    {
        const int tq = twlo + lo;
        const float pos = (float)segpos[tq];
        const bf16* qp = qkvb + (size_t)tq * 4096 + n * 128;
        float qv[4][8];
#pragma unroll
        for (int kc = 0; kc < 4; ++kc) {
            short8 raw = *(const short8*)(qp + kc * 32 + quad * 8);
            const bf16* rb = (const bf16*)&raw;
#pragma unroll
            for (int j = 0; j < 8; ++j) qv[kc][j] = b2f(rb[j]);
        }
#pragma unroll
        for (int kc = 0; kc < 2; ++kc)
#pragma unroll
            for (int j = 0; j < 8; ++j) {
                int hp = kc * 32 + quad * 8 + j;
                float ang = pos * __expf(-(float)hp * (1.0f / 64.0f) * LN_BASE);
                float sv, cv; __sincosf(ang, &sv, &cv);
                float first = qv[kc][j], second = qv[kc + 2][j];
                qv[kc][j]     = (first * cv - second * sv) * Q_SCALE;
                qv[kc + 2][j] = (second * cv + first * sv) * Q_SCALE;
            }
#pragma unroll
        for (int kc = 0; kc < 4; ++kc) {
            bf16 o[8];
#pragma unroll
            for (int j = 0; j < 8; ++j) o[j] = f2b(qv[kc][j]);
            qf[kc] = *(const short8*)o;
        }
    }

    floatx4 O[8];
#pragma unroll
    for (int i = 0; i < 8; ++i) O[i] = (floatx4){0.f, 0.f, 0.f, 0.f};
    float l_acc[4] = {0.f, 0.f, 0.f, 0.f};

    const int key_a = tid >> 3,      hd_a = (tid & 7) * 16;
    const int kp2   = (tid & 15) * 2, hd_b = (tid >> 4) * 8;

    const int s_start = (t0 > 1023) ? (t0 - 1024) : 0;
    const int nch = (t0 + 63 - s_start) / 32 + 1;

    const bf16* kg = qkvb + 2048 + kh * 128;
    const bf16* vg = qkvb + 3072 + kh * 128;

    short8 kr0 = *(const short8*)(kg + (size_t)(s_start + key_a) * 4096 + hd_a);
    short8 kr1 = *(const short8*)(kg + (size_t)(s_start + key_a) * 4096 + hd_a + 8);
    short8 vr0 = *(const short8*)(vg + (size_t)(s_start + kp2) * 4096 + hd_b);
    short8 vr1 = *(const short8*)(vg + (size_t)(s_start + kp2 + 1) * 4096 + hd_b);

    for (int c = 0; c < nch; ++c) {
        const int base = s_start + c * 32;
        const int buf = c & 1;

        *(short8*)&Ks[buf][key_a][hd_a]     = kr0;
        *(short8*)&Ks[buf][key_a][hd_a + 8] = kr1;
#pragma unroll
        for (int i = 0; i < 8; ++i) {
            unsigned pk = (unsigned)(unsigned short)vr0[i] |
                          ((unsigned)(unsigned short)vr1[i] << 16);
            *(unsigned*)&Vt[buf][hd_b + i][kp2] = pk;
        }
        if (c + 1 < nch) {
            const int nb = base + 32;
            kr0 = *(const short8*)(kg + (size_t)(nb + key_a) * 4096 + hd_a);
            kr1 = *(const short8*)(kg + (size_t)(nb + key_a) * 4096 + hd_a + 8);
            vr0 = *(const short8*)(vg + (size_t)(nb + kp2) * 4096 + hd_b);
            vr1 = *(const short8*)(vg + (size_t)(nb + kp2 + 1) * 4096 + hd_b);
        }
        __syncthreads();

        const int dbase = twlo - base;
        if (dbase >= -15 && dbase <= 1054) {
            floatx4 S0 = (floatx4){0.f, 0.f, 0.f, 0.f};
            floatx4 S1 = (floatx4){0.f, 0.f, 0.f, 0.f};
#pragma unroll
            for (int kc = 0; kc < 4; ++kc) {
                short8 b0 = *(const short8*)&Ks[buf][lo][kc * 32 + quad * 8];
                short8 b1 = *(const short8*)&Ks[buf][16 + lo][kc * 32 + quad * 8];
                S0 = __builtin_amdgcn_mfma_f32_16x16x32_bf16(qf[kc], b0, S0, 0, 0, 0);
                S1 = __builtin_amdgcn_mfma_f32_16x16x32_bf16(qf[kc], b1, S1, 0, 0, 0);
            }
            short8 vfrag[8];
#pragma unroll
            for (int nt = 0; nt < 8; ++nt)
                vfrag[nt] = *(const short8*)&Vt[buf][nt * 16 + lo][quad * 8];

            const bool need_mask = !(dbase >= 31 && dbase <= 1008);
            const int dq = dbase + quad * 4 - lo;
            float lg[2][4];
#pragma unroll
            for (int tau = 0; tau < 2; ++tau) {
#pragma unroll
                for (int r = 0; r < 4; ++r) {
                    float sv = (tau == 0) ? S0[r] : S1[r];
                    float ax = fabsf(sv) * (2.0f / SOFT_CAP);
                    float e2 = __expf(-ax);
                    float th = (1.0f - e2) * __builtin_amdgcn_rcpf(1.0f + e2);
                    float l  = copysignf(SOFT_CAP * th, sv);
                    float p  = __expf(l);
                    if (need_mask) {
                        int d = dq + r - tau * 16;
                        if ((unsigned)d > 1023u) p = 0.f;
                    }
                    lg[tau][r] = p;
                }
            }
#pragma unroll
            for (int r = 0; r < 4; ++r) l_acc[r] += lg[0][r] + lg[1][r];

#pragma unroll
            for (int tau = 0; tau < 2; ++tau)
#pragma unroll
                for (int r = 0; r < 4; ++r)
                    Ps[wave][quad * 4 + r][tau * 16 + lo] = f2b(lg[tau][r]);

            short8 pfrag = *(const short8*)&Ps[wave][lo][quad * 8];
#pragma unroll
            for (int nt = 0; nt < 8; ++nt)
                O[nt] = __builtin_amdgcn_mfma_f32_16x16x32_bf16(pfrag, vfrag[nt], O[nt], 0, 0, 0);
        }
    }

#pragma unroll
    for (int xm = 1; xm < 16; xm <<= 1)
#pragma unroll
        for (int r = 0; r < 4; ++r) l_acc[r] += __shfl_xor(l_acc[r], xm, 64);
    float invl[4];
#pragma unroll
    for (int r = 0; r < 4; ++r) invl[r] = 1.0f / l_acc[r];

#pragma unroll
    for (int nt = 0; nt < 8; ++nt)
#pragma unroll
        for (int r = 0; r < 4; ++r) {
            int t = twlo + quad * 4 + r;
            ebuf[(size_t)t * 2048 + n * 128 + nt * 16 + lo] = f2b(O[nt][r] * invl[r]);
        }
}

// ---------------------------------------------------------------------------
extern "C" void kernel_launch(void* const* d_in, const int* in_sizes, int n_in,
                              void* d_out, int out_size, void* d_ws, size_t ws_size,
                              hipStream_t stream)
{
    const float* x   = (const float*)d_in[0];
    const int*  segp = (const int*)d_in[1];
    // d_in[2] = attn_mask (bool) -- redundant with causal+window predicate, ignored
    const float* qk  = (const float*)d_in[3];
    const float* kvk = (const float*)d_in[4];
    const float* ok  = (const float*)d_in[5];

    // Workspace (48 MB): xb(0..8, aliased by ebuf) | WT_qkv(8..24) | WT_out(24..32) | qkvb(32..48)
    // After attn_k: WT_qkv and qkvb are dead -> reused as fp32 split-K partials P0/P1 (16 MB each).
    bf16* xb     = (bf16*)d_ws;
    bf16* ebuf   = xb;
    bf16* WT_qkv = xb + (size_t)4 * 1024 * 1024;
    bf16* WT_out = WT_qkv + (size_t)8 * 1024 * 1024;
    bf16* qkvb   = WT_out + (size_t)4 * 1024 * 1024;
    float* P0    = (float*)WT_qkv;
    float* P1    = (float*)qkvb;
    float* outp  = (float*)d_out;

    prep_k<<<dim3(14336), dim3(256), 0, stream>>>(x, qk, kvk, ok, xb, WT_qkv, WT_out);
    mfma_gemm_k<bf16><<<dim3(16, 32), dim3(256), 0, stream>>>(
        xb, WT_qkv, qkvb, 4096, 2048);
    rope_kk<<<dim3(T_DIM), dim3(256), 0, stream>>>(qkvb, segp);
    attn_k<<<dim3(T_DIM / 64, N_HEADS), dim3(256), 0, stream>>>(qkvb, segp, ebuf);
    mfma_gemm_splitk_k<<<dim3(16, 16, 2), dim3(256), 0, stream>>>(
        ebuf, WT_out, P0, P1);
    add_out_k<<<dim3(4096), dim3(256), 0, stream>>>(P0, P1, outp);
}